// Round 15
// baseline (677.860 us; speedup 1.0000x reference)
//
#include <hip/hip_runtime.h>

// PositiveWaveFunction: 32-step tanh RNN, batch 8192, hidden 1024.
// R15 = R14 resubmit (R14 failed to compile: a zero-width unicode char had
// corrupted the global_load_lds identifier inside TSTG; retyped clean).
// R14 = R13 (prefix-tree dedup, 600us) +
//  (1) tree levels 1..10 fused into ONE kernel (64 co-resident blocks,
//      device-scope grid barrier between levels; counters re-zeroed by prep1
//      each call -> deterministic). Replaces 10 small launches (~90us).
//  (2) gemm_step XCD-bijective swizzle: the 4 blocks sharing an A-tile land
//      on one XCD (A-band 2MB + B 2MB = L2-resident per XCD).
//  (3) s=31 skips the h-store (h31 only feeds the logit partials).

typedef __bf16 bf16;
typedef __bf16 bf16x8 __attribute__((ext_vector_type(8)));
typedef float  f32x4  __attribute__((ext_vector_type(4)));

#define HID   1024
#define BATCH 8192
#define NSPIN 32

#define AS1 __attribute__((address_space(1)))
#define AS3 __attribute__((address_space(3)))

__device__ __forceinline__ float tanh_fast(float x) {
    float ax = fabsf(x);
    float t  = __expf(-2.0f * ax);                       // (0,1], no overflow
    float r  = (1.0f - t) * __builtin_amdgcn_rcpf(1.0f + t);
    return __builtin_copysignf(r, x);
}

// ---------------- prep kernels ----------------

__global__ void prep1(const float* __restrict__ din, const float* __restrict__ Wih,
                      const float* __restrict__ Whh, const float* __restrict__ bih,
                      const float* __restrict__ bhh,
                      bf16* __restrict__ Wbf, float* __restrict__ u0, float* __restrict__ u1,
                      unsigned int* __restrict__ words, float* __restrict__ fact,
                      unsigned int* __restrict__ cnt) {
    long idx = (long)blockIdx.x * blockDim.x + threadIdx.x;
    long stride = (long)gridDim.x * blockDim.x;
    for (long i = idx; i < (long)HID * HID; i += stride) Wbf[i] = (bf16)Whh[i];
    for (long i = idx; i < HID; i += stride) {
        u0[i] = Wih[i * 2 + 0] + bih[i] + bhh[i];
        u1[i] = Wih[i * 2 + 1] + bih[i] + bhh[i];
    }
    for (long b = idx; b < BATCH; b += stride) {
        unsigned int wv = 0;
        for (int j = 0; j < 31; ++j)
            wv |= (din[((long)j * BATCH + b) * 2 + 1] != 0.0f ? 1u : 0u) << j;
        words[b] = wv;
    }
    if (idx < 16) cnt[idx] = 0;          // grid-barrier counters (every call)
    if (idx == 0) {  // factorials: float64 cumprod cast to float32, like reference
        double f = 1.0; fact[0] = 1.0f;
        for (int k = 1; k <= NSPIN; ++k) { f *= k; fact[k] = (float)f; }
    }
}

// single block: state0 = tanh(u0) (root of the tree) + its logits
__global__ void prep2(const float* __restrict__ u0, const float* __restrict__ Wlin,
                      const float* __restrict__ blin,
                      bf16* __restrict__ hrow, float* __restrict__ l0s) {
    __shared__ float red0[16], red1[16];
    int t = threadIdx.x;  // 0..1023
    float hv = tanh_fast(u0[t]);
    hrow[t] = (bf16)hv;
    float s0 = hv * Wlin[t], s1 = hv * Wlin[HID + t];
    #pragma unroll
    for (int off = 1; off < 64; off <<= 1) {
        s0 += __shfl_xor(s0, off, 64);
        s1 += __shfl_xor(s1, off, 64);
    }
    if ((t & 63) == 0) { red0[t >> 6] = s0; red1[t >> 6] = s1; }
    __syncthreads();
    if (t == 0) {
        float a = blin[0], b = blin[1];
        for (int i = 0; i < 16; ++i) { a += red0[i]; b += red1[i]; }
        l0s[0] = a; l0s[1] = b;
    }
}

// ---------------- shared tree-level macros ----------------
// geometry: 64-row x 128-col block tile, 8 waves (2x4 of 32x32), BK=64,
// 3-buffer counted-vmcnt pipeline. HIN = parent-state pointer.

#define TSTG(HIN, SA, SB, KT) do {                                                           \
    {                                                                                        \
        const int r_ = w * 8 + lrow;                                                         \
        const int sc_ = (lchk ^ (r_ & 7)) * 8;                                               \
        __builtin_amdgcn_global_load_lds(                                                    \
            (const AS1 void*)((HIN) + (rowM + r_) * HID + (KT) * 64 + sc_),                  \
            (AS3 void*)(&SA[(w * 8) * 64]), 16, 0, 0);                                       \
    }                                                                                        \
    _Pragma("unroll")                                                                        \
    for (int i = 0; i < 2; ++i) {                                                            \
        const int r_ = w * 16 + i * 8 + lrow;                                                \
        const int sc_ = (lchk ^ (r_ & 7)) * 8;                                               \
        __builtin_amdgcn_global_load_lds(                                                    \
            (const AS1 void*)(Wbf + (long)(colN + r_) * HID + (KT) * 64 + sc_),              \
            (AS3 void*)(&SB[(w * 16 + i * 8) * 64]), 16, 0, 0);                              \
    }                                                                                        \
} while (0)

#define TBODY(HIN, CA, CB, NA, NB, T) do {                                                   \
    bf16x8 af[2][2], bf_[2][2];                                                              \
    _Pragma("unroll")                                                                        \
    for (int kk = 0; kk < 2; ++kk) {                                                         \
        _Pragma("unroll")                                                                    \
        for (int m = 0; m < 2; ++m) {                                                        \
            const int ra_ = wr * 32 + m * 16 + fr;                                           \
            af[kk][m] = *(const bf16x8*)&CA[ra_ * 64 + ((kk * 32 + fq * 8) ^ ((ra_ & 7) << 3))]; \
        }                                                                                    \
        _Pragma("unroll")                                                                    \
        for (int n = 0; n < 2; ++n) {                                                        \
            const int rb_ = wc * 32 + n * 16 + fr;                                           \
            bf_[kk][n] = *(const bf16x8*)&CB[rb_ * 64 + ((kk * 32 + fq * 8) ^ ((rb_ & 7) << 3))]; \
        }                                                                                    \
    }                                                                                        \
    if ((T) <= 13) TSTG(HIN, NA, NB, (T) + 2);                                               \
    __builtin_amdgcn_s_setprio(1);                                                           \
    _Pragma("unroll")                                                                        \
    for (int kk = 0; kk < 2; ++kk)                                                           \
        _Pragma("unroll")                                                                    \
        for (int m = 0; m < 2; ++m)                                                          \
            _Pragma("unroll")                                                                \
            for (int n = 0; n < 2; ++n)                                                      \
                acc[m][n] = __builtin_amdgcn_mfma_f32_16x16x32_bf16(af[kk][m], bf_[kk][n], acc[m][n], 0, 0, 0); \
    __builtin_amdgcn_s_setprio(0);                                                           \
    __builtin_amdgcn_sched_barrier(0);                                                       \
    if ((T) <= 13)       asm volatile("s_waitcnt vmcnt(3)" ::: "memory");                    \
    else if ((T) == 14)  asm volatile("s_waitcnt vmcnt(0)" ::: "memory");                    \
    if ((T) <= 14) __builtin_amdgcn_s_barrier();                                             \
    __builtin_amdgcn_sched_barrier(0);                                                       \
} while (0)

#define TREE_KLOOP(HIN)                                                                      \
    TSTG(HIN, sA0, sB0, 0);                                                                  \
    TSTG(HIN, sA1, sB1, 1);                                                                  \
    __builtin_amdgcn_sched_barrier(0);                                                       \
    asm volatile("s_waitcnt vmcnt(3)" ::: "memory");                                         \
    __builtin_amdgcn_s_barrier();                                                            \
    __builtin_amdgcn_sched_barrier(0);                                                       \
    TBODY(HIN, sA0, sB0, sA2, sB2, 0);   TBODY(HIN, sA1, sB1, sA0, sB0, 1);                  \
    TBODY(HIN, sA2, sB2, sA1, sB1, 2);   TBODY(HIN, sA0, sB0, sA2, sB2, 3);                  \
    TBODY(HIN, sA1, sB1, sA0, sB0, 4);   TBODY(HIN, sA2, sB2, sA1, sB1, 5);                  \
    TBODY(HIN, sA0, sB0, sA2, sB2, 6);   TBODY(HIN, sA1, sB1, sA0, sB0, 7);                  \
    TBODY(HIN, sA2, sB2, sA1, sB1, 8);   TBODY(HIN, sA0, sB0, sA2, sB2, 9);                  \
    TBODY(HIN, sA1, sB1, sA0, sB0, 10);  TBODY(HIN, sA2, sB2, sA1, sB1, 11);                 \
    TBODY(HIN, sA0, sB0, sA2, sB2, 12);  TBODY(HIN, sA1, sB1, sA0, sB0, 13);                 \
    TBODY(HIN, sA2, sB2, sA1, sB1, 14);  TBODY(HIN, sA0, sB0, sA2, sB2, 15);

#define TREE_EPILOGUE(HOUT, SLOG, M)                                                         \
    float u0v[2], u1v[2], wl0[2], wl1[2];                                                    \
    int colg[2];                                                                             \
    _Pragma("unroll")                                                                        \
    for (int n = 0; n < 2; ++n) {                                                            \
        int c = colN + wc * 32 + n * 16 + fr;                                                \
        colg[n] = c;                                                                         \
        u0v[n] = u0[c]; u1v[n] = u1[c];                                                      \
        wl0[n] = Wlin[c]; wl1[n] = Wlin[HID + c];                                            \
    }                                                                                        \
    const int slot = colPanel * 4 + wc;                                                      \
    _Pragma("unroll")                                                                        \
    for (int m = 0; m < 2; ++m) {                                                            \
        _Pragma("unroll")                                                                    \
        for (int r = 0; r < 4; ++r) {                                                        \
            long p = rowM + wr * 32 + m * 16 + fq * 4 + r;                                   \
            if (p < (M)) {                                                                   \
                float s00 = 0.f, s01 = 0.f, s10 = 0.f, s11 = 0.f;                            \
                _Pragma("unroll")                                                            \
                for (int n = 0; n < 2; ++n) {                                                \
                    float z  = acc[m][n][r];                                                 \
                    float h0 = tanh_fast(z + u0v[n]);                                        \
                    float h1 = tanh_fast(z + u1v[n]);                                        \
                    (HOUT)[(2 * p + 0) * HID + colg[n]] = (bf16)h0;                          \
                    (HOUT)[(2 * p + 1) * HID + colg[n]] = (bf16)h1;                          \
                    s00 += h0 * wl0[n]; s01 += h0 * wl1[n];                                  \
                    s10 += h1 * wl0[n]; s11 += h1 * wl1[n];                                  \
                }                                                                            \
                _Pragma("unroll")                                                            \
                for (int off = 1; off < 16; off <<= 1) {                                     \
                    s00 += __shfl_xor(s00, off, 16);                                         \
                    s01 += __shfl_xor(s01, off, 16);                                         \
                    s10 += __shfl_xor(s10, off, 16);                                         \
                    s11 += __shfl_xor(s11, off, 16);                                         \
                }                                                                            \
                if (fr == 0) {                                                               \
                    *(float2*)&(SLOG)[(2 * p + 0) * 64 + slot * 2] = make_float2(s00, s01);  \
                    *(float2*)&(SLOG)[(2 * p + 1) * 64 + slot * 2] = make_float2(s10, s11);  \
                }                                                                            \
            }                                                                                \
        }                                                                                    \
    }

// ---------------- fused tree levels 1..10 (one kernel, grid barrier) --------
// 64 blocks (always co-resident). Block: col panel (128 cols) x row group
// (64 rows). Between levels: device-scope arrive+spin barrier (per-level
// counter slot, zeroed by prep1 each call).

__global__ __launch_bounds__(512, 2) void fused_tree(
        const bf16* __restrict__ hrow, bf16* __restrict__ hA, bf16* __restrict__ hB,
        const bf16* __restrict__ Wbf,
        const float* __restrict__ u0, const float* __restrict__ u1,
        const float* __restrict__ Wlin,
        float* __restrict__ slog, unsigned int* __restrict__ cnt) {
    __shared__ __align__(16) bf16 sA0[64 * 64];
    __shared__ __align__(16) bf16 sA1[64 * 64];
    __shared__ __align__(16) bf16 sA2[64 * 64];
    __shared__ __align__(16) bf16 sB0[128 * 64];
    __shared__ __align__(16) bf16 sB1[128 * 64];
    __shared__ __align__(16) bf16 sB2[128 * 64];

    const int tid = threadIdx.x;
    const int w = tid >> 6, l = tid & 63;
    const int px = blockIdx.x >> 3;          // row group 0..7
    const int colPanel = blockIdx.x & 7;     // col panel 0..7
    const long rowM = (long)px * 64;
    const int  colN = colPanel * 128;
    const int wr = w >> 2, wc = w & 3;
    const int fr = l & 15, fq = l >> 4;
    const int lrow = l >> 3, lchk = l & 7;

    const bf16* curin = hrow;
    bf16* curout = hA;

    for (int lvl = 1; lvl <= 10; ++lvl) {
        const int M = 1 << (lvl - 1);
        if (px < ((M + 63) >> 6)) {
            f32x4 acc[2][2] = {};
            float* slog_s = slog + ((long)(1 << lvl) - 2) * 64;
            TREE_KLOOP(curin)
            TREE_EPILOGUE(curout, slog_s, M)
        }
        // grid barrier (device scope)
        __syncthreads();
        if (tid == 0) {
            __threadfence();
            atomicAdd(&cnt[lvl], 1u);
            while (__hip_atomic_load(&cnt[lvl], __ATOMIC_ACQUIRE,
                                     __HIP_MEMORY_SCOPE_AGENT) < 64u)
                __builtin_amdgcn_s_sleep(2);
        }
        __syncthreads();
        curin = curout;
        curout = (curout == hA) ? hB : hA;
    }
}

// ---------------- standalone tree level (levels 11..13) ----------------

__global__ __launch_bounds__(512, 2) void tree_step(
        const bf16* __restrict__ hin, bf16* __restrict__ hout,
        const bf16* __restrict__ Wbf,
        const float* __restrict__ u0, const float* __restrict__ u1,
        const float* __restrict__ Wlin,
        float* __restrict__ slog_s, int M) {
    __shared__ __align__(16) bf16 sA0[64 * 64];
    __shared__ __align__(16) bf16 sA1[64 * 64];
    __shared__ __align__(16) bf16 sA2[64 * 64];
    __shared__ __align__(16) bf16 sB0[128 * 64];
    __shared__ __align__(16) bf16 sB1[128 * 64];
    __shared__ __align__(16) bf16 sB2[128 * 64];

    const int tid = threadIdx.x;
    const int w = tid >> 6, l = tid & 63;
    const long rowM = (long)blockIdx.x * 64;
    const int  colPanel = blockIdx.y;
    const int  colN = colPanel * 128;
    const int wr = w >> 2, wc = w & 3;
    const int fr = l & 15, fq = l >> 4;
    const int lrow = l >> 3, lchk = l & 7;

    f32x4 acc[2][2] = {};
    TREE_KLOOP(hin)
    TREE_EPILOGUE(hout, slog_s, M)
}

// gather: h_batch[b] = states13[p13(b)]
__global__ void gatherh(const bf16* __restrict__ states, const unsigned int* __restrict__ words,
                        bf16* __restrict__ hbatch) {
    long v = (long)blockIdx.x * blockDim.x + threadIdx.x;
    const long total = (long)BATCH * 128;
    for (; v < total; v += (long)gridDim.x * blockDim.x) {
        int b = (int)(v >> 7), c = (int)(v & 127);
        unsigned int p = __brev(words[b] & 0x1FFFu) >> 19;
        ((bf16x8*)hbatch)[v] = ((const bf16x8*)states)[(long)p * 128 + c];
    }
}

// ---------------- full-batch GEMM step (R7 structure + XCD swizzle) --------
// Tile 128x256, BK=64, 8 waves (2x4 of 64x64). 3-buffer LDS (A+B staged),
// counted vmcnt(6) boundaries. Blocks sharing an A-tile co-located per XCD.

__global__ __launch_bounds__(512, 2) void gemm_step(
        const bf16* __restrict__ hin, bf16* __restrict__ hout,
        const bf16* __restrict__ Wbf,
        const float* __restrict__ u0, const float* __restrict__ u1,
        const unsigned int* __restrict__ words, int sbit, int writeH,
        const float* __restrict__ Wlin,
        float* __restrict__ plog_s) {
    __shared__ __align__(16) bf16 sA0[128 * 64];
    __shared__ __align__(16) bf16 sA1[128 * 64];
    __shared__ __align__(16) bf16 sA2[128 * 64];
    __shared__ __align__(16) bf16 sB0[256 * 64];
    __shared__ __align__(16) bf16 sB1[256 * 64];
    __shared__ __align__(16) bf16 sB2[256 * 64];

    const int tid = threadIdx.x;
    const int w = tid >> 6, l = tid & 63;

    // XCD-bijective swizzle: lin -> (bx, by) with the 4 same-A blocks on one XCD
    const int lin = blockIdx.y * 64 + blockIdx.x;     // 0..255
    const int xcd = lin & 7, jj = lin >> 3;           // jj 0..31
    const long rowM = (long)(xcd * 8 + (jj >> 2)) * 128;
    const int  by   = jj & 3;
    const int  colN = by * 256;

    const int wr = w >> 2, wc = w & 3;      // 2x4 wave grid (64x64 tiles)
    const int fr = l & 15, fq = l >> 4;     // fragment lane coords

    f32x4 acc[4][4] = {};

    const int lrow = l >> 3;                 // 0..7
    const int lchk = l & 7;                  // 0..7 (16B chunk)

#define STG_A(SA, KT) do {                                                                   \
    _Pragma("unroll")                                                                        \
    for (int i = 0; i < 2; ++i) {                                                            \
        const int r_ = w * 16 + i * 8 + lrow;                                                \
        const int sc_ = (lchk ^ (r_ & 7)) * 8;                                               \
        __builtin_amdgcn_global_load_lds(                                                    \
            (const AS1 void*)(hin + (rowM + r_) * HID + (KT) * 64 + sc_),                    \
            (AS3 void*)(&SA[(w * 16 + i * 8) * 64]), 16, 0, 0);                              \
    }                                                                                        \
} while (0)

#define STG_B2(SB, KT, I0) do {                                                              \
    _Pragma("unroll")                                                                        \
    for (int i = (I0); i < (I0) + 2; ++i) {                                                  \
        const int r_ = w * 32 + i * 8 + lrow;                                                \
        const int sc_ = (lchk ^ (r_ & 7)) * 8;                                               \
        __builtin_amdgcn_global_load_lds(                                                    \
            (const AS1 void*)(Wbf + (long)(colN + r_) * HID + (KT) * 64 + sc_),              \
            (AS3 void*)(&SB[(w * 32 + i * 8) * 64]), 16, 0, 0);                              \
    }                                                                                        \
} while (0)

#define RD_FRAGS(AF, BF, SA, SB, KK) do {                                                    \
    _Pragma("unroll")                                                                        \
    for (int m = 0; m < 4; ++m) {                                                            \
        const int ra_ = wr * 64 + m * 16 + fr;                                               \
        AF[m] = *(const bf16x8*)&SA[ra_ * 64 + (((KK) * 32 + fq * 8) ^ ((ra_ & 7) << 3))];   \
    }                                                                                        \
    _Pragma("unroll")                                                                        \
    for (int n = 0; n < 4; ++n) {                                                            \
        const int rb_ = wc * 64 + n * 16 + fr;                                               \
        BF[n] = *(const bf16x8*)&SB[rb_ * 64 + (((KK) * 32 + fq * 8) ^ ((rb_ & 7) << 3))];   \
    }                                                                                        \
} while (0)

#define MFMA16(AF, BF) do {                                                                  \
    __builtin_amdgcn_s_setprio(1);                                                           \
    _Pragma("unroll")                                                                        \
    for (int m = 0; m < 4; ++m)                                                              \
        _Pragma("unroll")                                                                    \
        for (int n = 0; n < 4; ++n)                                                          \
            acc[m][n] = __builtin_amdgcn_mfma_f32_16x16x32_bf16(AF[m], BF[n], acc[m][n], 0, 0, 0); \
    __builtin_amdgcn_s_setprio(0);                                                           \
} while (0)

#define BODY(CA, CB, NA, NB, T) do {                                                         \
    bf16x8 afx[4], bfx[4], afy[4], bfy[4];                                                   \
    RD_FRAGS(afx, bfx, CA, CB, 0);                                                           \
    if ((T) <= 13) { STG_A(NA, (T) + 2); STG_B2(NB, (T) + 2, 0); }                           \
    MFMA16(afx, bfx);                                                                        \
    RD_FRAGS(afy, bfy, CA, CB, 1);                                                           \
    if ((T) <= 13) { STG_B2(NB, (T) + 2, 2); }                                               \
    MFMA16(afy, bfy);                                                                        \
    __builtin_amdgcn_sched_barrier(0);                                                       \
    if ((T) <= 13)       asm volatile("s_waitcnt vmcnt(6)" ::: "memory");                    \
    else if ((T) == 14)  asm volatile("s_waitcnt vmcnt(0)" ::: "memory");                    \
    if ((T) <= 14) __builtin_amdgcn_s_barrier();                                             \
    __builtin_amdgcn_sched_barrier(0);                                                       \
} while (0)

    STG_A(sA0, 0); STG_B2(sB0, 0, 0); STG_B2(sB0, 0, 2);
    STG_A(sA1, 1); STG_B2(sB1, 1, 0); STG_B2(sB1, 1, 2);
    __builtin_amdgcn_sched_barrier(0);
    asm volatile("s_waitcnt vmcnt(6)" ::: "memory");
    __builtin_amdgcn_s_barrier();
    __builtin_amdgcn_sched_barrier(0);

    BODY(sA0, sB0, sA2, sB2, 0);
    BODY(sA1, sB1, sA0, sB0, 1);
    BODY(sA2, sB2, sA1, sB1, 2);
    BODY(sA0, sB0, sA2, sB2, 3);
    BODY(sA1, sB1, sA0, sB0, 4);
    BODY(sA2, sB2, sA1, sB1, 5);
    BODY(sA0, sB0, sA2, sB2, 6);
    BODY(sA1, sB1, sA0, sB0, 7);
    BODY(sA2, sB2, sA1, sB1, 8);
    BODY(sA0, sB0, sA2, sB2, 9);
    BODY(sA1, sB1, sA0, sB0, 10);
    BODY(sA2, sB2, sA1, sB1, 11);
    BODY(sA0, sB0, sA2, sB2, 12);
    BODY(sA1, sB1, sA0, sB0, 13);
    BODY(sA2, sB2, sA1, sB1, 14);
    BODY(sA0, sB0, sA2, sB2, 15);

#undef BODY
#undef MFMA16
#undef RD_FRAGS
#undef STG_A
#undef STG_B2

    // epilogue: bias-select + tanh + (optional) bf16 store + partial logits
    float u0v[4], u1v[4], wl0[4], wl1[4];
    int colg[4];
    #pragma unroll
    for (int n = 0; n < 4; ++n) {
        int c = colN + wc * 64 + n * 16 + fr;
        colg[n] = c;
        u0v[n] = u0[c]; u1v[n] = u1[c];
        wl0[n] = Wlin[c]; wl1[n] = Wlin[HID + c];
    }
    const int slot = by * 4 + wc;   // 16 slots

    #pragma unroll
    for (int m = 0; m < 4; ++m) {
        #pragma unroll
        for (int r = 0; r < 4; ++r) {
            long rowg = rowM + wr * 64 + m * 16 + fq * 4 + r;
            int bt = (words[rowg] >> sbit) & 1;
            float s0 = 0.f, s1 = 0.f;
            #pragma unroll
            for (int n = 0; n < 4; ++n) {
                float z  = acc[m][n][r] + (bt ? u1v[n] : u0v[n]);
                float hv = tanh_fast(z);
                if (writeH) hout[rowg * HID + colg[n]] = (bf16)hv;
                s0 += hv * wl0[n];
                s1 += hv * wl1[n];
            }
            #pragma unroll
            for (int off = 1; off < 16; off <<= 1) {
                s0 += __shfl_xor(s0, off, 16);
                s1 += __shfl_xor(s1, off, 16);
            }
            if (fr == 0)
                *(float2*)&plog_s[rowg * 32 + slot * 2] = make_float2(s0, s1);
        }
    }
}

// ---------------- finalize: softmax + permutation weights ----------------

__global__ void finalize(const float* __restrict__ plog, const float* __restrict__ slog,
                         const float* __restrict__ l0s,
                         const float* __restrict__ blin, const unsigned int* __restrict__ words,
                         const float* __restrict__ fact, float* __restrict__ out) {
    long idx = (long)blockIdx.x * blockDim.x + threadIdx.x;
    if (idx >= (long)NSPIN * BATCH) return;
    int s = (int)(idx / BATCH), b = (int)(idx % BATCH);
    const unsigned int wv = words[b];

    float l0, l1;
    if (s == 0) { l0 = l0s[0]; l1 = l0s[1]; }
    else if (s <= 13) {
        unsigned int p = __brev(wv & ((1u << s) - 1)) >> (32 - s);
        const float* ps = slog + ((long)((1u << s) - 2) + p) * 64;
        l0 = blin[0]; l1 = blin[1];
        #pragma unroll
        for (int k = 0; k < 32; ++k) {
            l0 += ps[k * 2 + 0];
            l1 += ps[k * 2 + 1];
        }
    } else {
        l0 = blin[0]; l1 = blin[1];
        const float* ps = plog + ((long)(s - 14) * BATCH + b) * 32;
        #pragma unroll
        for (int k = 0; k < 16; ++k) {
            l0 += ps[k * 2 + 0];
            l1 += ps[k * 2 + 1];
        }
    }
    float mx = fmaxf(l0, l1);
    float e0 = __expf(l0 - mx), e1 = __expf(l1 - mx);
    float p0 = e0 / (e0 + e1), p1 = e1 / (e0 + e1);
    if (s > 0) {
        const int cd = __popc(wv & ((1u << s) - 1));
        const float cdf = (float)cd, cuf = (float)(s - cd);
        const float ku = 16.f - cuf, kd = 16.f - cdf;
        const int n = NSPIN - s;
        const int kui = (int)fminf(fmaxf(ku, 0.f), 32.f);
        const int kdi = (int)fminf(fmaxf(kd, 0.f), 32.f);
        const float wu = fact[n] / fact[kui] * (ku >= 0.f ? 1.f : 0.f) + 1e-12f;
        const float wd = fact[n] / fact[kdi] * (kd >= 0.f ? 1.f : 0.f) + 1e-12f;
        p0 *= wu; p1 *= wd;
    }
    float inv = 1.f / (p0 + p1);
    out[idx * 2 + 0] = p0 * inv;
    out[idx * 2 + 1] = p1 * inv;
}

// ---------------- launch ----------------

extern "C" void kernel_launch(void* const* d_in, const int* in_sizes, int n_in,
                              void* d_out, int out_size, void* d_ws, size_t ws_size,
                              hipStream_t stream) {
    const float* din  = (const float*)d_in[0];  // [32][8192][2]
    const float* Wih  = (const float*)d_in[1];  // [1024][2]
    const float* Whh  = (const float*)d_in[2];  // [1024][1024]
    const float* bih  = (const float*)d_in[3];  // [1024]
    const float* bhh  = (const float*)d_in[4];  // [1024]
    const float* Wlin = (const float*)d_in[5];  // [2][1024]
    const float* blin = (const float*)d_in[6];  // [2]
    float* out = (float*)d_out;

    char* ws = (char*)d_ws;
    size_t o = 0;
    auto alloc = [&](size_t b) { size_t r = o; o += (b + 255) & ~(size_t)255; return r; };
    bf16*  Wbf  = (bf16*)(ws + alloc((size_t)HID * HID * 2));
    float* u0   = (float*)(ws + alloc(HID * 4));
    float* u1   = (float*)(ws + alloc(HID * 4));
    bf16*  hrow = (bf16*)(ws + alloc((size_t)64 * HID * 2));   // 64-row padded root
    float* l0s  = (float*)(ws + alloc(2 * 4));
    float* fact = (float*)(ws + alloc(33 * 4));
    unsigned int* cnt = (unsigned int*)(ws + alloc(16 * 4));
    unsigned int* words = (unsigned int*)(ws + alloc((size_t)BATCH * 4));
    bf16*  hA   = (bf16*)(ws + alloc((size_t)BATCH * HID * 2));
    bf16*  hB   = (bf16*)(ws + alloc((size_t)BATCH * HID * 2));
    float* slog = (float*)(ws + alloc(((size_t)(1 << 14) - 2) * 64 * 4));  // ~4.2 MB
    float* plog = (float*)(ws + alloc(18L * BATCH * 32 * 4));              // 18.9 MB

    prep1<<<1024, 256, 0, stream>>>(din, Wih, Whh, bih, bhh, Wbf, u0, u1, words, fact, cnt);
    prep2<<<1, 1024, 0, stream>>>(u0, Wlin, blin, hrow, l0s);

    // tree levels 1..10 fused (out of level 10 lands in hB)
    fused_tree<<<64, 512, 0, stream>>>(hrow, hA, hB, Wbf, u0, u1, Wlin, slog, cnt);

    // levels 11..13 (in=hB -> hA -> hB -> hA)
    const bf16* tin = hB;
    bf16* tout = hA;
    for (int i = 11; i <= 13; ++i) {
        int Min = 1 << (i - 1);
        tree_step<<<dim3(Min / 64, 8), 512, 0, stream>>>(
            tin, tout, Wbf, u0, u1, Wlin,
            slog + ((long)(1 << i) - 2) * 64, Min);
        tin = tout;
        tout = (tout == hA) ? hB : hA;
    }
    // tin = states13 (hA); tout = hB
    gatherh<<<2048, 256, 0, stream>>>(tin, words, tout);   // hB = batch h13

    bf16* hin = tout;                       // hB
    bf16* hout = (tout == hA) ? hB : hA;    // hA
    for (int s = 14; s <= 31; ++s) {
        gemm_step<<<dim3(64, 4), 512, 0, stream>>>(
            hin, hout, Wbf, u0, u1, words, s - 1, (s < 31) ? 1 : 0, Wlin,
            plog + (size_t)(s - 14) * BATCH * 32);
        bf16* t = hin; hin = hout; hout = t;
    }
    finalize<<<(NSPIN * BATCH) / 256, 256, 0, stream>>>(plog, slog, l0s, blin, words, fact, out);
}

// Round 16
// 623.815 us; speedup vs baseline: 1.0866x; 1.0866x over previous
//
#include <hip/hip_runtime.h>

// PositiveWaveFunction: 32-step tanh RNN, batch 8192, hidden 1024.
// R16: R13 structure restored (per-level tree_step launches for all 13
// levels — R15's fused_tree grid-barrier variant measured 156us vs ~90us of
// launches, 95% idle; rejected). Keeps from R15: gemm_step XCD-bijective
// swizzle (4 same-A blocks per XCD -> A-band+B L2-resident) and the s=31
// h-store skip (saves a 17MB write).

typedef __bf16 bf16;
typedef __bf16 bf16x8 __attribute__((ext_vector_type(8)));
typedef float  f32x4  __attribute__((ext_vector_type(4)));

#define HID   1024
#define BATCH 8192
#define NSPIN 32

#define AS1 __attribute__((address_space(1)))
#define AS3 __attribute__((address_space(3)))

__device__ __forceinline__ float tanh_fast(float x) {
    float ax = fabsf(x);
    float t  = __expf(-2.0f * ax);                       // (0,1], no overflow
    float r  = (1.0f - t) * __builtin_amdgcn_rcpf(1.0f + t);
    return __builtin_copysignf(r, x);
}

// ---------------- prep kernels ----------------

__global__ void prep1(const float* __restrict__ din, const float* __restrict__ Wih,
                      const float* __restrict__ Whh, const float* __restrict__ bih,
                      const float* __restrict__ bhh,
                      bf16* __restrict__ Wbf, float* __restrict__ u0, float* __restrict__ u1,
                      unsigned int* __restrict__ words, float* __restrict__ fact) {
    long idx = (long)blockIdx.x * blockDim.x + threadIdx.x;
    long stride = (long)gridDim.x * blockDim.x;
    for (long i = idx; i < (long)HID * HID; i += stride) Wbf[i] = (bf16)Whh[i];
    for (long i = idx; i < HID; i += stride) {
        u0[i] = Wih[i * 2 + 0] + bih[i] + bhh[i];
        u1[i] = Wih[i * 2 + 1] + bih[i] + bhh[i];
    }
    for (long b = idx; b < BATCH; b += stride) {
        unsigned int wv = 0;
        for (int j = 0; j < 31; ++j)
            wv |= (din[((long)j * BATCH + b) * 2 + 1] != 0.0f ? 1u : 0u) << j;
        words[b] = wv;
    }
    if (idx == 0) {  // factorials: float64 cumprod cast to float32, like reference
        double f = 1.0; fact[0] = 1.0f;
        for (int k = 1; k <= NSPIN; ++k) { f *= k; fact[k] = (float)f; }
    }
}

// single block: state0 = tanh(u0) (root of the tree) + its logits
__global__ void prep2(const float* __restrict__ u0, const float* __restrict__ Wlin,
                      const float* __restrict__ blin,
                      bf16* __restrict__ hrow, float* __restrict__ l0s) {
    __shared__ float red0[16], red1[16];
    int t = threadIdx.x;  // 0..1023
    float hv = tanh_fast(u0[t]);
    hrow[t] = (bf16)hv;
    float s0 = hv * Wlin[t], s1 = hv * Wlin[HID + t];
    #pragma unroll
    for (int off = 1; off < 64; off <<= 1) {
        s0 += __shfl_xor(s0, off, 64);
        s1 += __shfl_xor(s1, off, 64);
    }
    if ((t & 63) == 0) { red0[t >> 6] = s0; red1[t >> 6] = s1; }
    __syncthreads();
    if (t == 0) {
        float a = blin[0], b = blin[1];
        for (int i = 0; i < 16; ++i) { a += red0[i]; b += red1[i]; }
        l0s[0] = a; l0s[1] = b;
    }
}

// ---------------- tree level kernel ----------------
// hin: M parent states (rows). For each parent p: Z = h_p @ W^T (1024 cols);
// children 2p+bit = tanh(Z + u_bit), both written to hout; per-child logit
// partials (32 cols/wave) -> slog_s[child][32 slots][2].
// Block tile 64x128, 8 waves (2x4 of 32x32), BK=64, 3-buffer counted vmcnt.

__global__ __launch_bounds__(512, 2) void tree_step(
        const bf16* __restrict__ hin, bf16* __restrict__ hout,
        const bf16* __restrict__ Wbf,
        const float* __restrict__ u0, const float* __restrict__ u1,
        const float* __restrict__ Wlin,
        float* __restrict__ slog_s, int M) {
    __shared__ __align__(16) bf16 sA0[64 * 64];
    __shared__ __align__(16) bf16 sA1[64 * 64];
    __shared__ __align__(16) bf16 sA2[64 * 64];
    __shared__ __align__(16) bf16 sB0[128 * 64];
    __shared__ __align__(16) bf16 sB1[128 * 64];
    __shared__ __align__(16) bf16 sB2[128 * 64];

    const int tid = threadIdx.x;
    const int w = tid >> 6, l = tid & 63;
    const long rowM = (long)blockIdx.x * 64;
    const int  colPanel = blockIdx.y;
    const int  colN = colPanel * 128;
    const int wr = w >> 2, wc = w & 3;      // 2x4 wave grid (32x32 tiles)
    const int fr = l & 15, fq = l >> 4;
    const int lrow = l >> 3, lchk = l & 7;

    f32x4 acc[2][2] = {};

#define TSTG(SA, SB, KT) do {                                                                \
    {                                                                                        \
        const int r_ = w * 8 + lrow;                                                         \
        const int sc_ = (lchk ^ (r_ & 7)) * 8;                                               \
        __builtin_amdgcn_global_load_lds(                                                    \
            (const AS1 void*)(hin + (rowM + r_) * HID + (KT) * 64 + sc_),                    \
            (AS3 void*)(&SA[(w * 8) * 64]), 16, 0, 0);                                       \
    }                                                                                        \
    _Pragma("unroll")                                                                        \
    for (int i = 0; i < 2; ++i) {                                                            \
        const int r_ = w * 16 + i * 8 + lrow;                                                \
        const int sc_ = (lchk ^ (r_ & 7)) * 8;                                               \
        __builtin_amdgcn_global_load_lds(                                                    \
            (const AS1 void*)(Wbf + (long)(colN + r_) * HID + (KT) * 64 + sc_),              \
            (AS3 void*)(&SB[(w * 16 + i * 8) * 64]), 16, 0, 0);                              \
    }                                                                                        \
} while (0)

#define TBODY(CA, CB, NA, NB, T) do {                                                        \
    bf16x8 af[2][2], bf_[2][2];                                                              \
    _Pragma("unroll")                                                                        \
    for (int kk = 0; kk < 2; ++kk) {                                                         \
        _Pragma("unroll")                                                                    \
        for (int m = 0; m < 2; ++m) {                                                        \
            const int ra_ = wr * 32 + m * 16 + fr;                                           \
            af[kk][m] = *(const bf16x8*)&CA[ra_ * 64 + ((kk * 32 + fq * 8) ^ ((ra_ & 7) << 3))]; \
        }                                                                                    \
        _Pragma("unroll")                                                                    \
        for (int n = 0; n < 2; ++n) {                                                        \
            const int rb_ = wc * 32 + n * 16 + fr;                                           \
            bf_[kk][n] = *(const bf16x8*)&CB[rb_ * 64 + ((kk * 32 + fq * 8) ^ ((rb_ & 7) << 3))]; \
        }                                                                                    \
    }                                                                                        \
    if ((T) <= 13) TSTG(NA, NB, (T) + 2);                                                    \
    __builtin_amdgcn_s_setprio(1);                                                           \
    _Pragma("unroll")                                                                        \
    for (int kk = 0; kk < 2; ++kk)                                                           \
        _Pragma("unroll")                                                                    \
        for (int m = 0; m < 2; ++m)                                                          \
            _Pragma("unroll")                                                                \
            for (int n = 0; n < 2; ++n)                                                      \
                acc[m][n] = __builtin_amdgcn_mfma_f32_16x16x32_bf16(af[kk][m], bf_[kk][n], acc[m][n], 0, 0, 0); \
    __builtin_amdgcn_s_setprio(0);                                                           \
    __builtin_amdgcn_sched_barrier(0);                                                       \
    if ((T) <= 13)       asm volatile("s_waitcnt vmcnt(3)" ::: "memory");                    \
    else if ((T) == 14)  asm volatile("s_waitcnt vmcnt(0)" ::: "memory");                    \
    if ((T) <= 14) __builtin_amdgcn_s_barrier();                                             \
    __builtin_amdgcn_sched_barrier(0);                                                       \
} while (0)

    TSTG(sA0, sB0, 0);
    TSTG(sA1, sB1, 1);
    __builtin_amdgcn_sched_barrier(0);
    asm volatile("s_waitcnt vmcnt(3)" ::: "memory");
    __builtin_amdgcn_s_barrier();
    __builtin_amdgcn_sched_barrier(0);

    TBODY(sA0, sB0, sA2, sB2, 0);   TBODY(sA1, sB1, sA0, sB0, 1);
    TBODY(sA2, sB2, sA1, sB1, 2);   TBODY(sA0, sB0, sA2, sB2, 3);
    TBODY(sA1, sB1, sA0, sB0, 4);   TBODY(sA2, sB2, sA1, sB1, 5);
    TBODY(sA0, sB0, sA2, sB2, 6);   TBODY(sA1, sB1, sA0, sB0, 7);
    TBODY(sA2, sB2, sA1, sB1, 8);   TBODY(sA0, sB0, sA2, sB2, 9);
    TBODY(sA1, sB1, sA0, sB0, 10);  TBODY(sA2, sB2, sA1, sB1, 11);
    TBODY(sA0, sB0, sA2, sB2, 12);  TBODY(sA1, sB1, sA0, sB0, 13);
    TBODY(sA2, sB2, sA1, sB1, 14);  TBODY(sA0, sB0, sA2, sB2, 15);

#undef TBODY
#undef TSTG

    // epilogue: both children + logit partials
    float u0v[2], u1v[2], wl0[2], wl1[2];
    int colg[2];
    #pragma unroll
    for (int n = 0; n < 2; ++n) {
        int c = colN + wc * 32 + n * 16 + fr;
        colg[n] = c;
        u0v[n] = u0[c]; u1v[n] = u1[c];
        wl0[n] = Wlin[c]; wl1[n] = Wlin[HID + c];
    }
    const int slot = colPanel * 4 + wc;   // 0..31

    #pragma unroll
    for (int m = 0; m < 2; ++m) {
        #pragma unroll
        for (int r = 0; r < 4; ++r) {
            long p = rowM + wr * 32 + m * 16 + fq * 4 + r;
            if (p < M) {
                float s00 = 0.f, s01 = 0.f, s10 = 0.f, s11 = 0.f;
                #pragma unroll
                for (int n = 0; n < 2; ++n) {
                    float z  = acc[m][n][r];
                    float h0 = tanh_fast(z + u0v[n]);
                    float h1 = tanh_fast(z + u1v[n]);
                    hout[(2 * p + 0) * HID + colg[n]] = (bf16)h0;
                    hout[(2 * p + 1) * HID + colg[n]] = (bf16)h1;
                    s00 += h0 * wl0[n]; s01 += h0 * wl1[n];
                    s10 += h1 * wl0[n]; s11 += h1 * wl1[n];
                }
                #pragma unroll
                for (int off = 1; off < 16; off <<= 1) {
                    s00 += __shfl_xor(s00, off, 16);
                    s01 += __shfl_xor(s01, off, 16);
                    s10 += __shfl_xor(s10, off, 16);
                    s11 += __shfl_xor(s11, off, 16);
                }
                if (fr == 0) {
                    *(float2*)&slog_s[(2 * p + 0) * 64 + slot * 2] = make_float2(s00, s01);
                    *(float2*)&slog_s[(2 * p + 1) * 64 + slot * 2] = make_float2(s10, s11);
                }
            }
        }
    }
}

// gather: h_batch[b] = states13[p13(b)]
__global__ void gatherh(const bf16* __restrict__ states, const unsigned int* __restrict__ words,
                        bf16* __restrict__ hbatch) {
    long v = (long)blockIdx.x * blockDim.x + threadIdx.x;
    const long total = (long)BATCH * 128;
    for (; v < total; v += (long)gridDim.x * blockDim.x) {
        int b = (int)(v >> 7), c = (int)(v & 127);
        unsigned int p = __brev(words[b] & 0x1FFFu) >> 19;
        ((bf16x8*)hbatch)[v] = ((const bf16x8*)states)[(long)p * 128 + c];
    }
}

// ---------------- full-batch GEMM step (R7 structure + XCD swizzle) --------
// Tile 128x256, BK=64, 8 waves (2x4 of 64x64). 3-buffer LDS (A+B staged),
// counted vmcnt(6) boundaries. Blocks sharing an A-tile co-located per XCD.

__global__ __launch_bounds__(512, 2) void gemm_step(
        const bf16* __restrict__ hin, bf16* __restrict__ hout,
        const bf16* __restrict__ Wbf,
        const float* __restrict__ u0, const float* __restrict__ u1,
        const unsigned int* __restrict__ words, int sbit, int writeH,
        const float* __restrict__ Wlin,
        float* __restrict__ plog_s) {
    __shared__ __align__(16) bf16 sA0[128 * 64];
    __shared__ __align__(16) bf16 sA1[128 * 64];
    __shared__ __align__(16) bf16 sA2[128 * 64];
    __shared__ __align__(16) bf16 sB0[256 * 64];
    __shared__ __align__(16) bf16 sB1[256 * 64];
    __shared__ __align__(16) bf16 sB2[256 * 64];

    const int tid = threadIdx.x;
    const int w = tid >> 6, l = tid & 63;

    // XCD-bijective swizzle: lin -> (bx, by) with the 4 same-A blocks on one XCD
    const int lin = blockIdx.y * 64 + blockIdx.x;     // 0..255
    const int xcd = lin & 7, jj = lin >> 3;           // jj 0..31
    const long rowM = (long)(xcd * 8 + (jj >> 2)) * 128;
    const int  by   = jj & 3;
    const int  colN = by * 256;

    const int wr = w >> 2, wc = w & 3;      // 2x4 wave grid (64x64 tiles)
    const int fr = l & 15, fq = l >> 4;     // fragment lane coords

    f32x4 acc[4][4] = {};

    const int lrow = l >> 3;                 // 0..7
    const int lchk = l & 7;                  // 0..7 (16B chunk)

#define STG_A(SA, KT) do {                                                                   \
    _Pragma("unroll")                                                                        \
    for (int i = 0; i < 2; ++i) {                                                            \
        const int r_ = w * 16 + i * 8 + lrow;                                                \
        const int sc_ = (lchk ^ (r_ & 7)) * 8;                                               \
        __builtin_amdgcn_global_load_lds(                                                    \
            (const AS1 void*)(hin + (rowM + r_) * HID + (KT) * 64 + sc_),                    \
            (AS3 void*)(&SA[(w * 16 + i * 8) * 64]), 16, 0, 0);                              \
    }                                                                                        \
} while (0)

#define STG_B2(SB, KT, I0) do {                                                              \
    _Pragma("unroll")                                                                        \
    for (int i = (I0); i < (I0) + 2; ++i) {                                                  \
        const int r_ = w * 32 + i * 8 + lrow;                                                \
        const int sc_ = (lchk ^ (r_ & 7)) * 8;                                               \
        __builtin_amdgcn_global_load_lds(                                                    \
            (const AS1 void*)(Wbf + (long)(colN + r_) * HID + (KT) * 64 + sc_),              \
            (AS3 void*)(&SB[(w * 32 + i * 8) * 64]), 16, 0, 0);                              \
    }                                                                                        \
} while (0)

#define RD_FRAGS(AF, BF, SA, SB, KK) do {                                                    \
    _Pragma("unroll")                                                                        \
    for (int m = 0; m < 4; ++m) {                                                            \
        const int ra_ = wr * 64 + m * 16 + fr;                                               \
        AF[m] = *(const bf16x8*)&SA[ra_ * 64 + (((KK) * 32 + fq * 8) ^ ((ra_ & 7) << 3))];   \
    }                                                                                        \
    _Pragma("unroll")                                                                        \
    for (int n = 0; n < 4; ++n) {                                                            \
        const int rb_ = wc * 64 + n * 16 + fr;                                               \
        BF[n] = *(const bf16x8*)&SB[rb_ * 64 + (((KK) * 32 + fq * 8) ^ ((rb_ & 7) << 3))];   \
    }                                                                                        \
} while (0)

#define MFMA16(AF, BF) do {                                                                  \
    __builtin_amdgcn_s_setprio(1);                                                           \
    _Pragma("unroll")                                                                        \
    for (int m = 0; m < 4; ++m)                                                              \
        _Pragma("unroll")                                                                    \
        for (int n = 0; n < 4; ++n)                                                          \
            acc[m][n] = __builtin_amdgcn_mfma_f32_16x16x32_bf16(AF[m], BF[n], acc[m][n], 0, 0, 0); \
    __builtin_amdgcn_s_setprio(0);                                                           \
} while (0)

#define BODY(CA, CB, NA, NB, T) do {                                                         \
    bf16x8 afx[4], bfx[4], afy[4], bfy[4];                                                   \
    RD_FRAGS(afx, bfx, CA, CB, 0);                                                           \
    if ((T) <= 13) { STG_A(NA, (T) + 2); STG_B2(NB, (T) + 2, 0); }                           \
    MFMA16(afx, bfx);                                                                        \
    RD_FRAGS(afy, bfy, CA, CB, 1);                                                           \
    if ((T) <= 13) { STG_B2(NB, (T) + 2, 2); }                                               \
    MFMA16(afy, bfy);                                                                        \
    __builtin_amdgcn_sched_barrier(0);                                                       \
    if ((T) <= 13)       asm volatile("s_waitcnt vmcnt(6)" ::: "memory");                    \
    else if ((T) == 14)  asm volatile("s_waitcnt vmcnt(0)" ::: "memory");                    \
    if ((T) <= 14) __builtin_amdgcn_s_barrier();                                             \
    __builtin_amdgcn_sched_barrier(0);                                                       \
} while (0)

    STG_A(sA0, 0); STG_B2(sB0, 0, 0); STG_B2(sB0, 0, 2);
    STG_A(sA1, 1); STG_B2(sB1, 1, 0); STG_B2(sB1, 1, 2);
    __builtin_amdgcn_sched_barrier(0);
    asm volatile("s_waitcnt vmcnt(6)" ::: "memory");
    __builtin_amdgcn_s_barrier();
    __builtin_amdgcn_sched_barrier(0);

    BODY(sA0, sB0, sA2, sB2, 0);
    BODY(sA1, sB1, sA0, sB0, 1);
    BODY(sA2, sB2, sA1, sB1, 2);
    BODY(sA0, sB0, sA2, sB2, 3);
    BODY(sA1, sB1, sA0, sB0, 4);
    BODY(sA2, sB2, sA1, sB1, 5);
    BODY(sA0, sB0, sA2, sB2, 6);
    BODY(sA1, sB1, sA0, sB0, 7);
    BODY(sA2, sB2, sA1, sB1, 8);
    BODY(sA0, sB0, sA2, sB2, 9);
    BODY(sA1, sB1, sA0, sB0, 10);
    BODY(sA2, sB2, sA1, sB1, 11);
    BODY(sA0, sB0, sA2, sB2, 12);
    BODY(sA1, sB1, sA0, sB0, 13);
    BODY(sA2, sB2, sA1, sB1, 14);
    BODY(sA0, sB0, sA2, sB2, 15);

#undef BODY
#undef MFMA16
#undef RD_FRAGS
#undef STG_A
#undef STG_B2

    // epilogue: bias-select + tanh + (optional) bf16 store + partial logits
    float u0v[4], u1v[4], wl0[4], wl1[4];
    int colg[4];
    #pragma unroll
    for (int n = 0; n < 4; ++n) {
        int c = colN + wc * 64 + n * 16 + fr;
        colg[n] = c;
        u0v[n] = u0[c]; u1v[n] = u1[c];
        wl0[n] = Wlin[c]; wl1[n] = Wlin[HID + c];
    }
    const int slot = by * 4 + wc;   // 16 slots

    #pragma unroll
    for (int m = 0; m < 4; ++m) {
        #pragma unroll
        for (int r = 0; r < 4; ++r) {
            long rowg = rowM + wr * 64 + m * 16 + fq * 4 + r;
            int bt = (words[rowg] >> sbit) & 1;
            float s0 = 0.f, s1 = 0.f;
            #pragma unroll
            for (int n = 0; n < 4; ++n) {
                float z  = acc[m][n][r] + (bt ? u1v[n] : u0v[n]);
                float hv = tanh_fast(z);
                if (writeH) hout[rowg * HID + colg[n]] = (bf16)hv;
                s0 += hv * wl0[n];
                s1 += hv * wl1[n];
            }
            #pragma unroll
            for (int off = 1; off < 16; off <<= 1) {
                s0 += __shfl_xor(s0, off, 16);
                s1 += __shfl_xor(s1, off, 16);
            }
            if (fr == 0)
                *(float2*)&plog_s[rowg * 32 + slot * 2] = make_float2(s0, s1);
        }
    }
}

// ---------------- finalize: softmax + permutation weights ----------------

__global__ void finalize(const float* __restrict__ plog, const float* __restrict__ slog,
                         const float* __restrict__ l0s,
                         const float* __restrict__ blin, const unsigned int* __restrict__ words,
                         const float* __restrict__ fact, float* __restrict__ out) {
    long idx = (long)blockIdx.x * blockDim.x + threadIdx.x;
    if (idx >= (long)NSPIN * BATCH) return;
    int s = (int)(idx / BATCH), b = (int)(idx % BATCH);
    const unsigned int wv = words[b];

    float l0, l1;
    if (s == 0) { l0 = l0s[0]; l1 = l0s[1]; }
    else if (s <= 13) {
        unsigned int p = __brev(wv & ((1u << s) - 1)) >> (32 - s);
        const float* ps = slog + ((long)((1u << s) - 2) + p) * 64;
        l0 = blin[0]; l1 = blin[1];
        #pragma unroll
        for (int k = 0; k < 32; ++k) {
            l0 += ps[k * 2 + 0];
            l1 += ps[k * 2 + 1];
        }
    } else {
        l0 = blin[0]; l1 = blin[1];
        const float* ps = plog + ((long)(s - 14) * BATCH + b) * 32;
        #pragma unroll
        for (int k = 0; k < 16; ++k) {
            l0 += ps[k * 2 + 0];
            l1 += ps[k * 2 + 1];
        }
    }
    float mx = fmaxf(l0, l1);
    float e0 = __expf(l0 - mx), e1 = __expf(l1 - mx);
    float p0 = e0 / (e0 + e1), p1 = e1 / (e0 + e1);
    if (s > 0) {
        const int cd = __popc(wv & ((1u << s) - 1));
        const float cdf = (float)cd, cuf = (float)(s - cd);
        const float ku = 16.f - cuf, kd = 16.f - cdf;
        const int n = NSPIN - s;
        const int kui = (int)fminf(fmaxf(ku, 0.f), 32.f);
        const int kdi = (int)fminf(fmaxf(kd, 0.f), 32.f);
        const float wu = fact[n] / fact[kui] * (ku >= 0.f ? 1.f : 0.f) + 1e-12f;
        const float wd = fact[n] / fact[kdi] * (kd >= 0.f ? 1.f : 0.f) + 1e-12f;
        p0 *= wu; p1 *= wd;
    }
    float inv = 1.f / (p0 + p1);
    out[idx * 2 + 0] = p0 * inv;
    out[idx * 2 + 1] = p1 * inv;
}

// ---------------- launch ----------------

extern "C" void kernel_launch(void* const* d_in, const int* in_sizes, int n_in,
                              void* d_out, int out_size, void* d_ws, size_t ws_size,
                              hipStream_t stream) {
    const float* din  = (const float*)d_in[0];  // [32][8192][2]
    const float* Wih  = (const float*)d_in[1];  // [1024][2]
    const float* Whh  = (const float*)d_in[2];  // [1024][1024]
    const float* bih  = (const float*)d_in[3];  // [1024]
    const float* bhh  = (const float*)d_in[4];  // [1024]
    const float* Wlin = (const float*)d_in[5];  // [2][1024]
    const float* blin = (const float*)d_in[6];  // [2]
    float* out = (float*)d_out;

    char* ws = (char*)d_ws;
    size_t o = 0;
    auto alloc = [&](size_t b) { size_t r = o; o += (b + 255) & ~(size_t)255; return r; };
    bf16*  Wbf  = (bf16*)(ws + alloc((size_t)HID * HID * 2));
    float* u0   = (float*)(ws + alloc(HID * 4));
    float* u1   = (float*)(ws + alloc(HID * 4));
    bf16*  hrow = (bf16*)(ws + alloc((size_t)64 * HID * 2));   // 64-row padded root
    float* l0s  = (float*)(ws + alloc(2 * 4));
    float* fact = (float*)(ws + alloc(33 * 4));
    unsigned int* words = (unsigned int*)(ws + alloc((size_t)BATCH * 4));
    bf16*  hA   = (bf16*)(ws + alloc((size_t)BATCH * HID * 2));
    bf16*  hB   = (bf16*)(ws + alloc((size_t)BATCH * HID * 2));
    float* slog = (float*)(ws + alloc(((size_t)(1 << 14) - 2) * 64 * 4));  // ~4.2 MB
    float* plog = (float*)(ws + alloc(18L * BATCH * 32 * 4));              // 18.9 MB

    prep1<<<1024, 256, 0, stream>>>(din, Wih, Whh, bih, bhh, Wbf, u0, u1, words, fact);
    prep2<<<1, 1024, 0, stream>>>(u0, Wlin, blin, hrow, l0s);

    // tree levels: level i consumes 2^(i-1) states, emits 2^i (states at step i)
    const bf16* tin = hrow;
    bf16* tout = hA;
    for (int i = 1; i <= 13; ++i) {
        int Min = 1 << (i - 1);
        dim3 g(Min < 64 ? 1 : Min / 64, 8);
        tree_step<<<g, 512, 0, stream>>>(
            tin, tout, Wbf, u0, u1, Wlin,
            slog + ((long)(1 << i) - 2) * 64, Min);
        tin = tout;
        tout = (tout == hA) ? hB : hA;
    }
    // tin = states13 (hA); tout = hB
    gatherh<<<2048, 256, 0, stream>>>(tin, words, tout);   // hB = batch h13

    bf16* hin = tout;                       // hB
    bf16* hout = (tout == hA) ? hB : hA;    // hA
    for (int s = 14; s <= 31; ++s) {
        gemm_step<<<dim3(64, 4), 512, 0, stream>>>(
            hin, hout, Wbf, u0, u1, words, s - 1, (s < 31) ? 1 : 0, Wlin,
            plog + (size_t)(s - 14) * BATCH * 32);
        bf16* t = hin; hin = hout; hout = t;
    }
    finalize<<<(NSPIN * BATCH) / 256, 256, 0, stream>>>(plog, slog, l0s, blin, words, fact, out);
}

// Round 17
// 608.682 us; speedup vs baseline: 1.1137x; 1.0249x over previous
//
#include <hip/hip_runtime.h>

// PositiveWaveFunction: 32-step tanh RNN, batch 8192, hidden 1024.
// R17 = R16 with:
//  (1) gemm_step XCD swizzle REVERTED (measured +25us cost in R16 — the
//      co-locate-same-A mapping forces every XCD to read all of B; default
//      x-major round-robin already groups same-B-panel blocks per XCD).
//  (2) gatherh kernel eliminated: s=14 gemm_step reads A-rows THROUGH the
//      prefix permutation (per-lane global_load_lds source = states13 +
//      pidx[row]*HID; LDS dest/swizzle keyed on LDS row, unchanged). pidx
//      precomputed in prep1. Bit-identical values, saves ~32MB move + launch.
//  Keeps: prefix-tree dedup (levels 1..13), 3-buffer counted-vmcnt pipeline,
//  s=31 h-store skip.

typedef __bf16 bf16;
typedef __bf16 bf16x8 __attribute__((ext_vector_type(8)));
typedef float  f32x4  __attribute__((ext_vector_type(4)));

#define HID   1024
#define BATCH 8192
#define NSPIN 32

#define AS1 __attribute__((address_space(1)))
#define AS3 __attribute__((address_space(3)))

__device__ __forceinline__ float tanh_fast(float x) {
    float ax = fabsf(x);
    float t  = __expf(-2.0f * ax);                       // (0,1], no overflow
    float r  = (1.0f - t) * __builtin_amdgcn_rcpf(1.0f + t);
    return __builtin_copysignf(r, x);
}

// ---------------- prep kernels ----------------

__global__ void prep1(const float* __restrict__ din, const float* __restrict__ Wih,
                      const float* __restrict__ Whh, const float* __restrict__ bih,
                      const float* __restrict__ bhh,
                      bf16* __restrict__ Wbf, float* __restrict__ u0, float* __restrict__ u1,
                      unsigned int* __restrict__ words, unsigned int* __restrict__ pidx,
                      float* __restrict__ fact) {
    long idx = (long)blockIdx.x * blockDim.x + threadIdx.x;
    long stride = (long)gridDim.x * blockDim.x;
    for (long i = idx; i < (long)HID * HID; i += stride) Wbf[i] = (bf16)Whh[i];
    for (long i = idx; i < HID; i += stride) {
        u0[i] = Wih[i * 2 + 0] + bih[i] + bhh[i];
        u1[i] = Wih[i * 2 + 1] + bih[i] + bhh[i];
    }
    for (long b = idx; b < BATCH; b += stride) {
        unsigned int wv = 0;
        for (int j = 0; j < 31; ++j)
            wv |= (din[((long)j * BATCH + b) * 2 + 1] != 0.0f ? 1u : 0u) << j;
        words[b] = wv;
        pidx[b] = __brev(wv & 0x1FFFu) >> 19;   // 13-bit prefix state index
    }
    if (idx == 0) {  // factorials: float64 cumprod cast to float32, like reference
        double f = 1.0; fact[0] = 1.0f;
        for (int k = 1; k <= NSPIN; ++k) { f *= k; fact[k] = (float)f; }
    }
}

// single block: state0 = tanh(u0) (root of the tree) + its logits
__global__ void prep2(const float* __restrict__ u0, const float* __restrict__ Wlin,
                      const float* __restrict__ blin,
                      bf16* __restrict__ hrow, float* __restrict__ l0s) {
    __shared__ float red0[16], red1[16];
    int t = threadIdx.x;  // 0..1023
    float hv = tanh_fast(u0[t]);
    hrow[t] = (bf16)hv;
    float s0 = hv * Wlin[t], s1 = hv * Wlin[HID + t];
    #pragma unroll
    for (int off = 1; off < 64; off <<= 1) {
        s0 += __shfl_xor(s0, off, 64);
        s1 += __shfl_xor(s1, off, 64);
    }
    if ((t & 63) == 0) { red0[t >> 6] = s0; red1[t >> 6] = s1; }
    __syncthreads();
    if (t == 0) {
        float a = blin[0], b = blin[1];
        for (int i = 0; i < 16; ++i) { a += red0[i]; b += red1[i]; }
        l0s[0] = a; l0s[1] = b;
    }
}

// ---------------- tree level kernel ----------------
// hin: M parent states (rows). For each parent p: Z = h_p @ W^T (1024 cols);
// children 2p+bit = tanh(Z + u_bit), both written to hout; per-child logit
// partials (32 cols/wave) -> slog_s[child][32 slots][2].
// Block tile 64x128, 8 waves (2x4 of 32x32), BK=64, 3-buffer counted vmcnt.

__global__ __launch_bounds__(512, 2) void tree_step(
        const bf16* __restrict__ hin, bf16* __restrict__ hout,
        const bf16* __restrict__ Wbf,
        const float* __restrict__ u0, const float* __restrict__ u1,
        const float* __restrict__ Wlin,
        float* __restrict__ slog_s, int M) {
    __shared__ __align__(16) bf16 sA0[64 * 64];
    __shared__ __align__(16) bf16 sA1[64 * 64];
    __shared__ __align__(16) bf16 sA2[64 * 64];
    __shared__ __align__(16) bf16 sB0[128 * 64];
    __shared__ __align__(16) bf16 sB1[128 * 64];
    __shared__ __align__(16) bf16 sB2[128 * 64];

    const int tid = threadIdx.x;
    const int w = tid >> 6, l = tid & 63;
    const long rowM = (long)blockIdx.x * 64;
    const int  colPanel = blockIdx.y;
    const int  colN = colPanel * 128;
    const int wr = w >> 2, wc = w & 3;      // 2x4 wave grid (32x32 tiles)
    const int fr = l & 15, fq = l >> 4;
    const int lrow = l >> 3, lchk = l & 7;

    f32x4 acc[2][2] = {};

#define TSTG(SA, SB, KT) do {                                                                \
    {                                                                                        \
        const int r_ = w * 8 + lrow;                                                         \
        const int sc_ = (lchk ^ (r_ & 7)) * 8;                                               \
        __builtin_amdgcn_global_load_lds(                                                    \
            (const AS1 void*)(hin + (rowM + r_) * HID + (KT) * 64 + sc_),                    \
            (AS3 void*)(&SA[(w * 8) * 64]), 16, 0, 0);                                       \
    }                                                                                        \
    _Pragma("unroll")                                                                        \
    for (int i = 0; i < 2; ++i) {                                                            \
        const int r_ = w * 16 + i * 8 + lrow;                                                \
        const int sc_ = (lchk ^ (r_ & 7)) * 8;                                               \
        __builtin_amdgcn_global_load_lds(                                                    \
            (const AS1 void*)(Wbf + (long)(colN + r_) * HID + (KT) * 64 + sc_),              \
            (AS3 void*)(&SB[(w * 16 + i * 8) * 64]), 16, 0, 0);                              \
    }                                                                                        \
} while (0)

#define TBODY(CA, CB, NA, NB, T) do {                                                        \
    bf16x8 af[2][2], bf_[2][2];                                                              \
    _Pragma("unroll")                                                                        \
    for (int kk = 0; kk < 2; ++kk) {                                                         \
        _Pragma("unroll")                                                                    \
        for (int m = 0; m < 2; ++m) {                                                        \
            const int ra_ = wr * 32 + m * 16 + fr;                                           \
            af[kk][m] = *(const bf16x8*)&CA[ra_ * 64 + ((kk * 32 + fq * 8) ^ ((ra_ & 7) << 3))]; \
        }                                                                                    \
        _Pragma("unroll")                                                                    \
        for (int n = 0; n < 2; ++n) {                                                        \
            const int rb_ = wc * 32 + n * 16 + fr;                                           \
            bf_[kk][n] = *(const bf16x8*)&CB[rb_ * 64 + ((kk * 32 + fq * 8) ^ ((rb_ & 7) << 3))]; \
        }                                                                                    \
    }                                                                                        \
    if ((T) <= 13) TSTG(NA, NB, (T) + 2);                                                    \
    __builtin_amdgcn_s_setprio(1);                                                           \
    _Pragma("unroll")                                                                        \
    for (int kk = 0; kk < 2; ++kk)                                                           \
        _Pragma("unroll")                                                                    \
        for (int m = 0; m < 2; ++m)                                                          \
            _Pragma("unroll")                                                                \
            for (int n = 0; n < 2; ++n)                                                      \
                acc[m][n] = __builtin_amdgcn_mfma_f32_16x16x32_bf16(af[kk][m], bf_[kk][n], acc[m][n], 0, 0, 0); \
    __builtin_amdgcn_s_setprio(0);                                                           \
    __builtin_amdgcn_sched_barrier(0);                                                       \
    if ((T) <= 13)       asm volatile("s_waitcnt vmcnt(3)" ::: "memory");                    \
    else if ((T) == 14)  asm volatile("s_waitcnt vmcnt(0)" ::: "memory");                    \
    if ((T) <= 14) __builtin_amdgcn_s_barrier();                                             \
    __builtin_amdgcn_sched_barrier(0);                                                       \
} while (0)

    TSTG(sA0, sB0, 0);
    TSTG(sA1, sB1, 1);
    __builtin_amdgcn_sched_barrier(0);
    asm volatile("s_waitcnt vmcnt(3)" ::: "memory");
    __builtin_amdgcn_s_barrier();
    __builtin_amdgcn_sched_barrier(0);

    TBODY(sA0, sB0, sA2, sB2, 0);   TBODY(sA1, sB1, sA0, sB0, 1);
    TBODY(sA2, sB2, sA1, sB1, 2);   TBODY(sA0, sB0, sA2, sB2, 3);
    TBODY(sA1, sB1, sA0, sB0, 4);   TBODY(sA2, sB2, sA1, sB1, 5);
    TBODY(sA0, sB0, sA2, sB2, 6);   TBODY(sA1, sB1, sA0, sB0, 7);
    TBODY(sA2, sB2, sA1, sB1, 8);   TBODY(sA0, sB0, sA2, sB2, 9);
    TBODY(sA1, sB1, sA0, sB0, 10);  TBODY(sA2, sB2, sA1, sB1, 11);
    TBODY(sA0, sB0, sA2, sB2, 12);  TBODY(sA1, sB1, sA0, sB0, 13);
    TBODY(sA2, sB2, sA1, sB1, 14);  TBODY(sA0, sB0, sA2, sB2, 15);

#undef TBODY
#undef TSTG

    // epilogue: both children + logit partials
    float u0v[2], u1v[2], wl0[2], wl1[2];
    int colg[2];
    #pragma unroll
    for (int n = 0; n < 2; ++n) {
        int c = colN + wc * 32 + n * 16 + fr;
        colg[n] = c;
        u0v[n] = u0[c]; u1v[n] = u1[c];
        wl0[n] = Wlin[c]; wl1[n] = Wlin[HID + c];
    }
    const int slot = colPanel * 4 + wc;   // 0..31

    #pragma unroll
    for (int m = 0; m < 2; ++m) {
        #pragma unroll
        for (int r = 0; r < 4; ++r) {
            long p = rowM + wr * 32 + m * 16 + fq * 4 + r;
            if (p < M) {
                float s00 = 0.f, s01 = 0.f, s10 = 0.f, s11 = 0.f;
                #pragma unroll
                for (int n = 0; n < 2; ++n) {
                    float z  = acc[m][n][r];
                    float h0 = tanh_fast(z + u0v[n]);
                    float h1 = tanh_fast(z + u1v[n]);
                    hout[(2 * p + 0) * HID + colg[n]] = (bf16)h0;
                    hout[(2 * p + 1) * HID + colg[n]] = (bf16)h1;
                    s00 += h0 * wl0[n]; s01 += h0 * wl1[n];
                    s10 += h1 * wl0[n]; s11 += h1 * wl1[n];
                }
                #pragma unroll
                for (int off = 1; off < 16; off <<= 1) {
                    s00 += __shfl_xor(s00, off, 16);
                    s01 += __shfl_xor(s01, off, 16);
                    s10 += __shfl_xor(s10, off, 16);
                    s11 += __shfl_xor(s11, off, 16);
                }
                if (fr == 0) {
                    *(float2*)&slog_s[(2 * p + 0) * 64 + slot * 2] = make_float2(s00, s01);
                    *(float2*)&slog_s[(2 * p + 1) * 64 + slot * 2] = make_float2(s10, s11);
                }
            }
        }
    }
}

// ---------------- full-batch GEMM step (R7 structure, default mapping) ----
// Tile 128x256, BK=64, 8 waves (2x4 of 64x64). 3-buffer LDS (A+B staged),
// counted vmcnt(6) boundaries. pidx != null (s=14 only): A-rows read through
// the prefix permutation (per-lane global source; LDS layout unchanged).

__global__ __launch_bounds__(512, 2) void gemm_step(
        const bf16* __restrict__ hin, bf16* __restrict__ hout,
        const bf16* __restrict__ Wbf,
        const float* __restrict__ u0, const float* __restrict__ u1,
        const unsigned int* __restrict__ words,
        const unsigned int* __restrict__ pidx, int sbit, int writeH,
        const float* __restrict__ Wlin,
        float* __restrict__ plog_s) {
    __shared__ __align__(16) bf16 sA0[128 * 64];
    __shared__ __align__(16) bf16 sA1[128 * 64];
    __shared__ __align__(16) bf16 sA2[128 * 64];
    __shared__ __align__(16) bf16 sB0[256 * 64];
    __shared__ __align__(16) bf16 sB1[256 * 64];
    __shared__ __align__(16) bf16 sB2[256 * 64];

    const int tid = threadIdx.x;
    const int w = tid >> 6, l = tid & 63;
    const long rowM = (long)blockIdx.x * 128;
    const int  by   = blockIdx.y;
    const int  colN = by * 256;

    const int wr = w >> 2, wc = w & 3;      // 2x4 wave grid (64x64 tiles)
    const int fr = l & 15, fq = l >> 4;     // fragment lane coords

    f32x4 acc[4][4] = {};

    const int lrow = l >> 3;                 // 0..7
    const int lchk = l & 7;                  // 0..7 (16B chunk)

    // per-lane A source row bases (identity, or prefix-permuted for s=14).
    // These loads retire before the first staging issue (address dependency),
    // so in-loop vmcnt counting is unaffected.
    long arow0 = rowM + w * 16 + 0 + lrow;
    long arow1 = rowM + w * 16 + 8 + lrow;
    if (pidx) { arow0 = pidx[arow0]; arow1 = pidx[arow1]; }

#define STG_A(SA, KT) do {                                                                   \
    {                                                                                        \
        const int r_ = w * 16 + 0 + lrow;                                                    \
        const int sc_ = (lchk ^ (r_ & 7)) * 8;                                               \
        __builtin_amdgcn_global_load_lds(                                                    \
            (const AS1 void*)(hin + arow0 * HID + (KT) * 64 + sc_),                          \
            (AS3 void*)(&SA[(w * 16 + 0) * 64]), 16, 0, 0);                                  \
    }                                                                                        \
    {                                                                                        \
        const int r_ = w * 16 + 8 + lrow;                                                    \
        const int sc_ = (lchk ^ (r_ & 7)) * 8;                                               \
        __builtin_amdgcn_global_load_lds(                                                    \
            (const AS1 void*)(hin + arow1 * HID + (KT) * 64 + sc_),                          \
            (AS3 void*)(&SA[(w * 16 + 8) * 64]), 16, 0, 0);                                  \
    }                                                                                        \
} while (0)

#define STG_B2(SB, KT, I0) do {                                                              \
    _Pragma("unroll")                                                                        \
    for (int i = (I0); i < (I0) + 2; ++i) {                                                  \
        const int r_ = w * 32 + i * 8 + lrow;                                                \
        const int sc_ = (lchk ^ (r_ & 7)) * 8;                                               \
        __builtin_amdgcn_global_load_lds(                                                    \
            (const AS1 void*)(Wbf + (long)(colN + r_) * HID + (KT) * 64 + sc_),              \
            (AS3 void*)(&SB[(w * 32 + i * 8) * 64]), 16, 0, 0);                              \
    }                                                                                        \
} while (0)

#define RD_FRAGS(AF, BF, SA, SB, KK) do {                                                    \
    _Pragma("unroll")                                                                        \
    for (int m = 0; m < 4; ++m) {                                                            \
        const int ra_ = wr * 64 + m * 16 + fr;                                               \
        AF[m] = *(const bf16x8*)&SA[ra_ * 64 + (((KK) * 32 + fq * 8) ^ ((ra_ & 7) << 3))];   \
    }                                                                                        \
    _Pragma("unroll")                                                                        \
    for (int n = 0; n < 4; ++n) {                                                            \
        const int rb_ = wc * 64 + n * 16 + fr;                                               \
        BF[n] = *(const bf16x8*)&SB[rb_ * 64 + (((KK) * 32 + fq * 8) ^ ((rb_ & 7) << 3))];   \
    }                                                                                        \
} while (0)

#define MFMA16(AF, BF) do {                                                                  \
    __builtin_amdgcn_s_setprio(1);                                                           \
    _Pragma("unroll")                                                                        \
    for (int m = 0; m < 4; ++m)                                                              \
        _Pragma("unroll")                                                                    \
        for (int n = 0; n < 4; ++n)                                                          \
            acc[m][n] = __builtin_amdgcn_mfma_f32_16x16x32_bf16(AF[m], BF[n], acc[m][n], 0, 0, 0); \
    __builtin_amdgcn_s_setprio(0);                                                           \
} while (0)

#define BODY(CA, CB, NA, NB, T) do {                                                         \
    bf16x8 afx[4], bfx[4], afy[4], bfy[4];                                                   \
    RD_FRAGS(afx, bfx, CA, CB, 0);                                                           \
    if ((T) <= 13) { STG_A(NA, (T) + 2); STG_B2(NB, (T) + 2, 0); }                           \
    MFMA16(afx, bfx);                                                                        \
    RD_FRAGS(afy, bfy, CA, CB, 1);                                                           \
    if ((T) <= 13) { STG_B2(NB, (T) + 2, 2); }                                               \
    MFMA16(afy, bfy);                                                                        \
    __builtin_amdgcn_sched_barrier(0);                                                       \
    if ((T) <= 13)       asm volatile("s_waitcnt vmcnt(6)" ::: "memory");                    \
    else if ((T) == 14)  asm volatile("s_waitcnt vmcnt(0)" ::: "memory");                    \
    if ((T) <= 14) __builtin_amdgcn_s_barrier();                                             \
    __builtin_amdgcn_sched_barrier(0);                                                       \
} while (0)

    STG_A(sA0, 0); STG_B2(sB0, 0, 0); STG_B2(sB0, 0, 2);
    STG_A(sA1, 1); STG_B2(sB1, 1, 0); STG_B2(sB1, 1, 2);
    __builtin_amdgcn_sched_barrier(0);
    asm volatile("s_waitcnt vmcnt(6)" ::: "memory");
    __builtin_amdgcn_s_barrier();
    __builtin_amdgcn_sched_barrier(0);

    BODY(sA0, sB0, sA2, sB2, 0);
    BODY(sA1, sB1, sA0, sB0, 1);
    BODY(sA2, sB2, sA1, sB1, 2);
    BODY(sA0, sB0, sA2, sB2, 3);
    BODY(sA1, sB1, sA0, sB0, 4);
    BODY(sA2, sB2, sA1, sB1, 5);
    BODY(sA0, sB0, sA2, sB2, 6);
    BODY(sA1, sB1, sA0, sB0, 7);
    BODY(sA2, sB2, sA1, sB1, 8);
    BODY(sA0, sB0, sA2, sB2, 9);
    BODY(sA1, sB1, sA0, sB0, 10);
    BODY(sA2, sB2, sA1, sB1, 11);
    BODY(sA0, sB0, sA2, sB2, 12);
    BODY(sA1, sB1, sA0, sB0, 13);
    BODY(sA2, sB2, sA1, sB1, 14);
    BODY(sA0, sB0, sA2, sB2, 15);

#undef BODY
#undef MFMA16
#undef RD_FRAGS
#undef STG_A
#undef STG_B2

    // epilogue: bias-select + tanh + (optional) bf16 store + partial logits
    float u0v[4], u1v[4], wl0[4], wl1[4];
    int colg[4];
    #pragma unroll
    for (int n = 0; n < 4; ++n) {
        int c = colN + wc * 64 + n * 16 + fr;
        colg[n] = c;
        u0v[n] = u0[c]; u1v[n] = u1[c];
        wl0[n] = Wlin[c]; wl1[n] = Wlin[HID + c];
    }
    const int slot = by * 4 + wc;   // 16 slots

    #pragma unroll
    for (int m = 0; m < 4; ++m) {
        #pragma unroll
        for (int r = 0; r < 4; ++r) {
            long rowg = rowM + wr * 64 + m * 16 + fq * 4 + r;
            int bt = (words[rowg] >> sbit) & 1;
            float s0 = 0.f, s1 = 0.f;
            #pragma unroll
            for (int n = 0; n < 4; ++n) {
                float z  = acc[m][n][r] + (bt ? u1v[n] : u0v[n]);
                float hv = tanh_fast(z);
                if (writeH) hout[rowg * HID + colg[n]] = (bf16)hv;
                s0 += hv * wl0[n];
                s1 += hv * wl1[n];
            }
            #pragma unroll
            for (int off = 1; off < 16; off <<= 1) {
                s0 += __shfl_xor(s0, off, 16);
                s1 += __shfl_xor(s1, off, 16);
            }
            if (fr == 0)
                *(float2*)&plog_s[rowg * 32 + slot * 2] = make_float2(s0, s1);
        }
    }
}

// ---------------- finalize: softmax + permutation weights ----------------

__global__ void finalize(const float* __restrict__ plog, const float* __restrict__ slog,
                         const float* __restrict__ l0s,
                         const float* __restrict__ blin, const unsigned int* __restrict__ words,
                         const float* __restrict__ fact, float* __restrict__ out) {
    long idx = (long)blockIdx.x * blockDim.x + threadIdx.x;
    if (idx >= (long)NSPIN * BATCH) return;
    int s = (int)(idx / BATCH), b = (int)(idx % BATCH);
    const unsigned int wv = words[b];

    float l0, l1;
    if (s == 0) { l0 = l0s[0]; l1 = l0s[1]; }
    else if (s <= 13) {
        unsigned int p = __brev(wv & ((1u << s) - 1)) >> (32 - s);
        const float* ps = slog + ((long)((1u << s) - 2) + p) * 64;
        l0 = blin[0]; l1 = blin[1];
        #pragma unroll
        for (int k = 0; k < 32; ++k) {
            l0 += ps[k * 2 + 0];
            l1 += ps[k * 2 + 1];
        }
    } else {
        l0 = blin[0]; l1 = blin[1];
        const float* ps = plog + ((long)(s - 14) * BATCH + b) * 32;
        #pragma unroll
        for (int k = 0; k < 16; ++k) {
            l0 += ps[k * 2 + 0];
            l1 += ps[k * 2 + 1];
        }
    }
    float mx = fmaxf(l0, l1);
    float e0 = __expf(l0 - mx), e1 = __expf(l1 - mx);
    float p0 = e0 / (e0 + e1), p1 = e1 / (e0 + e1);
    if (s > 0) {
        const int cd = __popc(wv & ((1u << s) - 1));
        const float cdf = (float)cd, cuf = (float)(s - cd);
        const float ku = 16.f - cuf, kd = 16.f - cdf;
        const int n = NSPIN - s;
        const int kui = (int)fminf(fmaxf(ku, 0.f), 32.f);
        const int kdi = (int)fminf(fmaxf(kd, 0.f), 32.f);
        const float wu = fact[n] / fact[kui] * (ku >= 0.f ? 1.f : 0.f) + 1e-12f;
        const float wd = fact[n] / fact[kdi] * (kd >= 0.f ? 1.f : 0.f) + 1e-12f;
        p0 *= wu; p1 *= wd;
    }
    float inv = 1.f / (p0 + p1);
    out[idx * 2 + 0] = p0 * inv;
    out[idx * 2 + 1] = p1 * inv;
}

// ---------------- launch ----------------

extern "C" void kernel_launch(void* const* d_in, const int* in_sizes, int n_in,
                              void* d_out, int out_size, void* d_ws, size_t ws_size,
                              hipStream_t stream) {
    const float* din  = (const float*)d_in[0];  // [32][8192][2]
    const float* Wih  = (const float*)d_in[1];  // [1024][2]
    const float* Whh  = (const float*)d_in[2];  // [1024][1024]
    const float* bih  = (const float*)d_in[3];  // [1024]
    const float* bhh  = (const float*)d_in[4];  // [1024]
    const float* Wlin = (const float*)d_in[5];  // [2][1024]
    const float* blin = (const float*)d_in[6];  // [2]
    float* out = (float*)d_out;

    char* ws = (char*)d_ws;
    size_t o = 0;
    auto alloc = [&](size_t b) { size_t r = o; o += (b + 255) & ~(size_t)255; return r; };
    bf16*  Wbf  = (bf16*)(ws + alloc((size_t)HID * HID * 2));
    float* u0   = (float*)(ws + alloc(HID * 4));
    float* u1   = (float*)(ws + alloc(HID * 4));
    bf16*  hrow = (bf16*)(ws + alloc((size_t)64 * HID * 2));   // 64-row padded root
    float* l0s  = (float*)(ws + alloc(2 * 4));
    float* fact = (float*)(ws + alloc(33 * 4));
    unsigned int* words = (unsigned int*)(ws + alloc((size_t)BATCH * 4));
    unsigned int* pidx  = (unsigned int*)(ws + alloc((size_t)BATCH * 4));
    bf16*  hA   = (bf16*)(ws + alloc((size_t)BATCH * HID * 2));
    bf16*  hB   = (bf16*)(ws + alloc((size_t)BATCH * HID * 2));
    float* slog = (float*)(ws + alloc(((size_t)(1 << 14) - 2) * 64 * 4));  // ~4.2 MB
    float* plog = (float*)(ws + alloc(18L * BATCH * 32 * 4));              // 18.9 MB

    prep1<<<1024, 256, 0, stream>>>(din, Wih, Whh, bih, bhh, Wbf, u0, u1, words, pidx, fact);
    prep2<<<1, 1024, 0, stream>>>(u0, Wlin, blin, hrow, l0s);

    // tree levels: level i consumes 2^(i-1) states, emits 2^i (states at step i)
    const bf16* tin = hrow;
    bf16* tout = hA;
    for (int i = 1; i <= 13; ++i) {
        int Min = 1 << (i - 1);
        dim3 g(Min < 64 ? 1 : Min / 64, 8);
        tree_step<<<g, 512, 0, stream>>>(
            tin, tout, Wbf, u0, u1, Wlin,
            slog + ((long)(1 << i) - 2) * 64, Min);
        tin = tout;
        tout = (tout == hA) ? hB : hA;
    }
    // tin = states13 (hA); s=14 reads through pidx permutation directly.
    bf16* hin = (bf16*)tin;                 // hA (states13)
    bf16* hout = (tin == hA) ? hB : hA;     // hB
    for (int s = 14; s <= 31; ++s) {
        gemm_step<<<dim3(64, 4), 512, 0, stream>>>(
            hin, hout, Wbf, u0, u1, words,
            (s == 14) ? pidx : (const unsigned int*)nullptr,
            s - 1, (s < 31) ? 1 : 0, Wlin,
            plog + (size_t)(s - 14) * BATCH * 32);
        bf16* t = hin; hin = hout; hout = t;
    }
    finalize<<<(NSPIN * BATCH) / 256, 256, 0, stream>>>(plog, slog, l0s, blin, words, fact, out);
}

// Round 18
// 602.444 us; speedup vs baseline: 1.1252x; 1.0104x over previous
//
#include <hip/hip_runtime.h>

// PositiveWaveFunction: 32-step tanh RNN, batch 8192, hidden 1024.
// R18 = R17 + tree_step BK=128 (8 K-tiles instead of 16): halves the
// boundary-barrier chain of the 13 latency-dominated tree launches.
// LDS 3x(16KB A + 32KB B) = 144KB; 6 loads/wave/tile -> vmcnt(6) boundaries;
// same sequential K accumulation order -> bit-identical output.
// Keeps: prefix-tree dedup, gather-through-permutation s=14, default block
// mapping (XCD swizzle measured -25us in R16), s=31 h-store skip.

typedef __bf16 bf16;
typedef __bf16 bf16x8 __attribute__((ext_vector_type(8)));
typedef float  f32x4  __attribute__((ext_vector_type(4)));

#define HID   1024
#define BATCH 8192
#define NSPIN 32

#define AS1 __attribute__((address_space(1)))
#define AS3 __attribute__((address_space(3)))

__device__ __forceinline__ float tanh_fast(float x) {
    float ax = fabsf(x);
    float t  = __expf(-2.0f * ax);                       // (0,1], no overflow
    float r  = (1.0f - t) * __builtin_amdgcn_rcpf(1.0f + t);
    return __builtin_copysignf(r, x);
}

// ---------------- prep kernels ----------------

__global__ void prep1(const float* __restrict__ din, const float* __restrict__ Wih,
                      const float* __restrict__ Whh, const float* __restrict__ bih,
                      const float* __restrict__ bhh,
                      bf16* __restrict__ Wbf, float* __restrict__ u0, float* __restrict__ u1,
                      unsigned int* __restrict__ words, unsigned int* __restrict__ pidx,
                      float* __restrict__ fact) {
    long idx = (long)blockIdx.x * blockDim.x + threadIdx.x;
    long stride = (long)gridDim.x * blockDim.x;
    for (long i = idx; i < (long)HID * HID; i += stride) Wbf[i] = (bf16)Whh[i];
    for (long i = idx; i < HID; i += stride) {
        u0[i] = Wih[i * 2 + 0] + bih[i] + bhh[i];
        u1[i] = Wih[i * 2 + 1] + bih[i] + bhh[i];
    }
    for (long b = idx; b < BATCH; b += stride) {
        unsigned int wv = 0;
        for (int j = 0; j < 31; ++j)
            wv |= (din[((long)j * BATCH + b) * 2 + 1] != 0.0f ? 1u : 0u) << j;
        words[b] = wv;
        pidx[b] = __brev(wv & 0x1FFFu) >> 19;   // 13-bit prefix state index
    }
    if (idx == 0) {  // factorials: float64 cumprod cast to float32, like reference
        double f = 1.0; fact[0] = 1.0f;
        for (int k = 1; k <= NSPIN; ++k) { f *= k; fact[k] = (float)f; }
    }
}

// single block: state0 = tanh(u0) (root of the tree) + its logits
__global__ void prep2(const float* __restrict__ u0, const float* __restrict__ Wlin,
                      const float* __restrict__ blin,
                      bf16* __restrict__ hrow, float* __restrict__ l0s) {
    __shared__ float red0[16], red1[16];
    int t = threadIdx.x;  // 0..1023
    float hv = tanh_fast(u0[t]);
    hrow[t] = (bf16)hv;
    float s0 = hv * Wlin[t], s1 = hv * Wlin[HID + t];
    #pragma unroll
    for (int off = 1; off < 64; off <<= 1) {
        s0 += __shfl_xor(s0, off, 64);
        s1 += __shfl_xor(s1, off, 64);
    }
    if ((t & 63) == 0) { red0[t >> 6] = s0; red1[t >> 6] = s1; }
    __syncthreads();
    if (t == 0) {
        float a = blin[0], b = blin[1];
        for (int i = 0; i < 16; ++i) { a += red0[i]; b += red1[i]; }
        l0s[0] = a; l0s[1] = b;
    }
}

// ---------------- tree level kernel (BK=128, 8 K-tiles) ----------------
// hin: M parent states. Z = h_p @ W^T; children 2p+bit = tanh(Z + u_bit);
// per-child logit partials -> slog_s[child][32 slots][2].
// Block tile 64x128, 8 waves (2x4 of 32x32). 3-buffer counted vmcnt(6).
// 256B LDS rows: 4 rows/instr (lrow=l>>4), 16 chunks (lchk=l&15),
// swizzle chunk ^= row&15 (2-way banks, free).

__global__ __launch_bounds__(512, 2) void tree_step(
        const bf16* __restrict__ hin, bf16* __restrict__ hout,
        const bf16* __restrict__ Wbf,
        const float* __restrict__ u0, const float* __restrict__ u1,
        const float* __restrict__ Wlin,
        float* __restrict__ slog_s, int M) {
    __shared__ __align__(16) bf16 sA0[64 * 128];
    __shared__ __align__(16) bf16 sA1[64 * 128];
    __shared__ __align__(16) bf16 sA2[64 * 128];
    __shared__ __align__(16) bf16 sB0[128 * 128];
    __shared__ __align__(16) bf16 sB1[128 * 128];
    __shared__ __align__(16) bf16 sB2[128 * 128];

    const int tid = threadIdx.x;
    const int w = tid >> 6, l = tid & 63;
    const long rowM = (long)blockIdx.x * 64;
    const int  colPanel = blockIdx.y;
    const int  colN = colPanel * 128;
    const int wr = w >> 2, wc = w & 3;      // 2x4 wave grid (32x32 tiles)
    const int fr = l & 15, fq = l >> 4;
    const int lrow = l >> 4, lchk = l & 15;  // 4 rows x 16 chunks per instr

    f32x4 acc[2][2] = {};

#define TSTG(SA, SB, KT) do {                                                                \
    _Pragma("unroll")                                                                        \
    for (int i = 0; i < 2; ++i) {                                                            \
        const int r_ = w * 8 + i * 4 + lrow;                                                 \
        const int sc_ = (lchk ^ (r_ & 15)) * 8;                                              \
        __builtin_amdgcn_global_load_lds(                                                    \
            (const AS1 void*)(hin + (rowM + r_) * HID + (KT) * 128 + sc_),                   \
            (AS3 void*)(&SA[(w * 8 + i * 4) * 128]), 16, 0, 0);                              \
    }                                                                                        \
    _Pragma("unroll")                                                                        \
    for (int i = 0; i < 4; ++i) {                                                            \
        const int r_ = w * 16 + i * 4 + lrow;                                                \
        const int sc_ = (lchk ^ (r_ & 15)) * 8;                                              \
        __builtin_amdgcn_global_load_lds(                                                    \
            (const AS1 void*)(Wbf + (long)(colN + r_) * HID + (KT) * 128 + sc_),             \
            (AS3 void*)(&SB[(w * 16 + i * 4) * 128]), 16, 0, 0);                             \
    }                                                                                        \
} while (0)

#define TBODY(CA, CB, NA, NB, T) do {                                                        \
    bf16x8 af[4][2], bf_[4][2];                                                              \
    _Pragma("unroll")                                                                        \
    for (int kk = 0; kk < 4; ++kk) {                                                         \
        _Pragma("unroll")                                                                    \
        for (int m = 0; m < 2; ++m) {                                                        \
            const int ra_ = wr * 32 + m * 16 + fr;                                           \
            af[kk][m] = *(const bf16x8*)&CA[ra_ * 128 + ((kk * 32 + fq * 8) ^ ((ra_ & 15) << 3))]; \
        }                                                                                    \
        _Pragma("unroll")                                                                    \
        for (int n = 0; n < 2; ++n) {                                                        \
            const int rb_ = wc * 32 + n * 16 + fr;                                           \
            bf_[kk][n] = *(const bf16x8*)&CB[rb_ * 128 + ((kk * 32 + fq * 8) ^ ((rb_ & 15) << 3))]; \
        }                                                                                    \
    }                                                                                        \
    if ((T) <= 5) TSTG(NA, NB, (T) + 2);                                                     \
    __builtin_amdgcn_s_setprio(1);                                                           \
    _Pragma("unroll")                                                                        \
    for (int kk = 0; kk < 4; ++kk)                                                           \
        _Pragma("unroll")                                                                    \
        for (int m = 0; m < 2; ++m)                                                          \
            _Pragma("unroll")                                                                \
            for (int n = 0; n < 2; ++n)                                                      \
                acc[m][n] = __builtin_amdgcn_mfma_f32_16x16x32_bf16(af[kk][m], bf_[kk][n], acc[m][n], 0, 0, 0); \
    __builtin_amdgcn_s_setprio(0);                                                           \
    __builtin_amdgcn_sched_barrier(0);                                                       \
    if ((T) <= 5)        asm volatile("s_waitcnt vmcnt(6)" ::: "memory");                    \
    else if ((T) == 6)   asm volatile("s_waitcnt vmcnt(0)" ::: "memory");                    \
    if ((T) <= 6) __builtin_amdgcn_s_barrier();                                              \
    __builtin_amdgcn_sched_barrier(0);                                                       \
} while (0)

    TSTG(sA0, sB0, 0);
    TSTG(sA1, sB1, 1);
    __builtin_amdgcn_sched_barrier(0);
    asm volatile("s_waitcnt vmcnt(6)" ::: "memory");
    __builtin_amdgcn_s_barrier();
    __builtin_amdgcn_sched_barrier(0);

    TBODY(sA0, sB0, sA2, sB2, 0);
    TBODY(sA1, sB1, sA0, sB0, 1);
    TBODY(sA2, sB2, sA1, sB1, 2);
    TBODY(sA0, sB0, sA2, sB2, 3);
    TBODY(sA1, sB1, sA0, sB0, 4);
    TBODY(sA2, sB2, sA1, sB1, 5);
    TBODY(sA0, sB0, sA2, sB2, 6);
    TBODY(sA1, sB1, sA2, sB2, 7);

#undef TBODY
#undef TSTG

    // epilogue: both children + logit partials
    float u0v[2], u1v[2], wl0[2], wl1[2];
    int colg[2];
    #pragma unroll
    for (int n = 0; n < 2; ++n) {
        int c = colN + wc * 32 + n * 16 + fr;
        colg[n] = c;
        u0v[n] = u0[c]; u1v[n] = u1[c];
        wl0[n] = Wlin[c]; wl1[n] = Wlin[HID + c];
    }
    const int slot = colPanel * 4 + wc;   // 0..31

    #pragma unroll
    for (int m = 0; m < 2; ++m) {
        #pragma unroll
        for (int r = 0; r < 4; ++r) {
            long p = rowM + wr * 32 + m * 16 + fq * 4 + r;
            if (p < M) {
                float s00 = 0.f, s01 = 0.f, s10 = 0.f, s11 = 0.f;
                #pragma unroll
                for (int n = 0; n < 2; ++n) {
                    float z  = acc[m][n][r];
                    float h0 = tanh_fast(z + u0v[n]);
                    float h1 = tanh_fast(z + u1v[n]);
                    hout[(2 * p + 0) * HID + colg[n]] = (bf16)h0;
                    hout[(2 * p + 1) * HID + colg[n]] = (bf16)h1;
                    s00 += h0 * wl0[n]; s01 += h0 * wl1[n];
                    s10 += h1 * wl0[n]; s11 += h1 * wl1[n];
                }
                #pragma unroll
                for (int off = 1; off < 16; off <<= 1) {
                    s00 += __shfl_xor(s00, off, 16);
                    s01 += __shfl_xor(s01, off, 16);
                    s10 += __shfl_xor(s10, off, 16);
                    s11 += __shfl_xor(s11, off, 16);
                }
                if (fr == 0) {
                    *(float2*)&slog_s[(2 * p + 0) * 64 + slot * 2] = make_float2(s00, s01);
                    *(float2*)&slog_s[(2 * p + 1) * 64 + slot * 2] = make_float2(s10, s11);
                }
            }
        }
    }
}

// ---------------- full-batch GEMM step (R7 structure, default mapping) ----
// Tile 128x256, BK=64, 8 waves (2x4 of 64x64). 3-buffer LDS (A+B staged),
// counted vmcnt(6) boundaries. pidx != null (s=14 only): A-rows read through
// the prefix permutation (per-lane global source; LDS layout unchanged).

__global__ __launch_bounds__(512, 2) void gemm_step(
        const bf16* __restrict__ hin, bf16* __restrict__ hout,
        const bf16* __restrict__ Wbf,
        const float* __restrict__ u0, const float* __restrict__ u1,
        const unsigned int* __restrict__ words,
        const unsigned int* __restrict__ pidx, int sbit, int writeH,
        const float* __restrict__ Wlin,
        float* __restrict__ plog_s) {
    __shared__ __align__(16) bf16 sA0[128 * 64];
    __shared__ __align__(16) bf16 sA1[128 * 64];
    __shared__ __align__(16) bf16 sA2[128 * 64];
    __shared__ __align__(16) bf16 sB0[256 * 64];
    __shared__ __align__(16) bf16 sB1[256 * 64];
    __shared__ __align__(16) bf16 sB2[256 * 64];

    const int tid = threadIdx.x;
    const int w = tid >> 6, l = tid & 63;
    const long rowM = (long)blockIdx.x * 128;
    const int  by   = blockIdx.y;
    const int  colN = by * 256;

    const int wr = w >> 2, wc = w & 3;      // 2x4 wave grid (64x64 tiles)
    const int fr = l & 15, fq = l >> 4;     // fragment lane coords

    f32x4 acc[4][4] = {};

    const int lrow = l >> 3;                 // 0..7
    const int lchk = l & 7;                  // 0..7 (16B chunk)

    // per-lane A source row bases (identity, or prefix-permuted for s=14).
    long arow0 = rowM + w * 16 + 0 + lrow;
    long arow1 = rowM + w * 16 + 8 + lrow;
    if (pidx) { arow0 = pidx[arow0]; arow1 = pidx[arow1]; }

#define STG_A(SA, KT) do {                                                                   \
    {                                                                                        \
        const int r_ = w * 16 + 0 + lrow;                                                    \
        const int sc_ = (lchk ^ (r_ & 7)) * 8;                                               \
        __builtin_amdgcn_global_load_lds(                                                    \
            (const AS1 void*)(hin + arow0 * HID + (KT) * 64 + sc_),                          \
            (AS3 void*)(&SA[(w * 16 + 0) * 64]), 16, 0, 0);                                  \
    }                                                                                        \
    {                                                                                        \
        const int r_ = w * 16 + 8 + lrow;                                                    \
        const int sc_ = (lchk ^ (r_ & 7)) * 8;                                               \
        __builtin_amdgcn_global_load_lds(                                                    \
            (const AS1 void*)(hin + arow1 * HID + (KT) * 64 + sc_),                          \
            (AS3 void*)(&SA[(w * 16 + 8) * 64]), 16, 0, 0);                                  \
    }                                                                                        \
} while (0)

#define STG_B2(SB, KT, I0) do {                                                              \
    _Pragma("unroll")                                                                        \
    for (int i = (I0); i < (I0) + 2; ++i) {                                                  \
        const int r_ = w * 32 + i * 8 + lrow;                                                \
        const int sc_ = (lchk ^ (r_ & 7)) * 8;                                               \
        __builtin_amdgcn_global_load_lds(                                                    \
            (const AS1 void*)(Wbf + (long)(colN + r_) * HID + (KT) * 64 + sc_),              \
            (AS3 void*)(&SB[(w * 32 + i * 8) * 64]), 16, 0, 0);                              \
    }                                                                                        \
} while (0)

#define RD_FRAGS(AF, BF, SA, SB, KK) do {                                                    \
    _Pragma("unroll")                                                                        \
    for (int m = 0; m < 4; ++m) {                                                            \
        const int ra_ = wr * 64 + m * 16 + fr;                                               \
        AF[m] = *(const bf16x8*)&SA[ra_ * 64 + (((KK) * 32 + fq * 8) ^ ((ra_ & 7) << 3))];   \
    }                                                                                        \
    _Pragma("unroll")                                                                        \
    for (int n = 0; n < 4; ++n) {                                                            \
        const int rb_ = wc * 64 + n * 16 + fr;                                               \
        BF[n] = *(const bf16x8*)&SB[rb_ * 64 + (((KK) * 32 + fq * 8) ^ ((rb_ & 7) << 3))];   \
    }                                                                                        \
} while (0)

#define MFMA16(AF, BF) do {                                                                  \
    __builtin_amdgcn_s_setprio(1);                                                           \
    _Pragma("unroll")                                                                        \
    for (int m = 0; m < 4; ++m)                                                              \
        _Pragma("unroll")                                                                    \
        for (int n = 0; n < 4; ++n)                                                          \
            acc[m][n] = __builtin_amdgcn_mfma_f32_16x16x32_bf16(AF[m], BF[n], acc[m][n], 0, 0, 0); \
    __builtin_amdgcn_s_setprio(0);                                                           \
} while (0)

#define BODY(CA, CB, NA, NB, T) do {                                                         \
    bf16x8 afx[4], bfx[4], afy[4], bfy[4];                                                   \
    RD_FRAGS(afx, bfx, CA, CB, 0);                                                           \
    if ((T) <= 13) { STG_A(NA, (T) + 2); STG_B2(NB, (T) + 2, 0); }                           \
    MFMA16(afx, bfx);                                                                        \
    RD_FRAGS(afy, bfy, CA, CB, 1);                                                           \
    if ((T) <= 13) { STG_B2(NB, (T) + 2, 2); }                                               \
    MFMA16(afy, bfy);                                                                        \
    __builtin_amdgcn_sched_barrier(0);                                                       \
    if ((T) <= 13)       asm volatile("s_waitcnt vmcnt(6)" ::: "memory");                    \
    else if ((T) == 14)  asm volatile("s_waitcnt vmcnt(0)" ::: "memory");                    \
    if ((T) <= 14) __builtin_amdgcn_s_barrier();                                             \
    __builtin_amdgcn_sched_barrier(0);                                                       \
} while (0)

    STG_A(sA0, 0); STG_B2(sB0, 0, 0); STG_B2(sB0, 0, 2);
    STG_A(sA1, 1); STG_B2(sB1, 1, 0); STG_B2(sB1, 1, 2);
    __builtin_amdgcn_sched_barrier(0);
    asm volatile("s_waitcnt vmcnt(6)" ::: "memory");
    __builtin_amdgcn_s_barrier();
    __builtin_amdgcn_sched_barrier(0);

    BODY(sA0, sB0, sA2, sB2, 0);
    BODY(sA1, sB1, sA0, sB0, 1);
    BODY(sA2, sB2, sA1, sB1, 2);
    BODY(sA0, sB0, sA2, sB2, 3);
    BODY(sA1, sB1, sA0, sB0, 4);
    BODY(sA2, sB2, sA1, sB1, 5);
    BODY(sA0, sB0, sA2, sB2, 6);
    BODY(sA1, sB1, sA0, sB0, 7);
    BODY(sA2, sB2, sA1, sB1, 8);
    BODY(sA0, sB0, sA2, sB2, 9);
    BODY(sA1, sB1, sA0, sB0, 10);
    BODY(sA2, sB2, sA1, sB1, 11);
    BODY(sA0, sB0, sA2, sB2, 12);
    BODY(sA1, sB1, sA0, sB0, 13);
    BODY(sA2, sB2, sA1, sB1, 14);
    BODY(sA0, sB0, sA2, sB2, 15);

#undef BODY
#undef MFMA16
#undef RD_FRAGS
#undef STG_A
#undef STG_B2

    // epilogue: bias-select + tanh + (optional) bf16 store + partial logits
    float u0v[4], u1v[4], wl0[4], wl1[4];
    int colg[4];
    #pragma unroll
    for (int n = 0; n < 4; ++n) {
        int c = colN + wc * 64 + n * 16 + fr;
        colg[n] = c;
        u0v[n] = u0[c]; u1v[n] = u1[c];
        wl0[n] = Wlin[c]; wl1[n] = Wlin[HID + c];
    }
    const int slot = by * 4 + wc;   // 16 slots

    #pragma unroll
    for (int m = 0; m < 4; ++m) {
        #pragma unroll
        for (int r = 0; r < 4; ++r) {
            long rowg = rowM + wr * 64 + m * 16 + fq * 4 + r;
            int bt = (words[rowg] >> sbit) & 1;
            float s0 = 0.f, s1 = 0.f;
            #pragma unroll
            for (int n = 0; n < 4; ++n) {
                float z  = acc[m][n][r] + (bt ? u1v[n] : u0v[n]);
                float hv = tanh_fast(z);
                if (writeH) hout[rowg * HID + colg[n]] = (bf16)hv;
                s0 += hv * wl0[n];
                s1 += hv * wl1[n];
            }
            #pragma unroll
            for (int off = 1; off < 16; off <<= 1) {
                s0 += __shfl_xor(s0, off, 16);
                s1 += __shfl_xor(s1, off, 16);
            }
            if (fr == 0)
                *(float2*)&plog_s[rowg * 32 + slot * 2] = make_float2(s0, s1);
        }
    }
}

// ---------------- finalize: softmax + permutation weights ----------------

__global__ void finalize(const float* __restrict__ plog, const float* __restrict__ slog,
                         const float* __restrict__ l0s,
                         const float* __restrict__ blin, const unsigned int* __restrict__ words,
                         const float* __restrict__ fact, float* __restrict__ out) {
    long idx = (long)blockIdx.x * blockDim.x + threadIdx.x;
    if (idx >= (long)NSPIN * BATCH) return;
    int s = (int)(idx / BATCH), b = (int)(idx % BATCH);
    const unsigned int wv = words[b];

    float l0, l1;
    if (s == 0) { l0 = l0s[0]; l1 = l0s[1]; }
    else if (s <= 13) {
        unsigned int p = __brev(wv & ((1u << s) - 1)) >> (32 - s);
        const float* ps = slog + ((long)((1u << s) - 2) + p) * 64;
        l0 = blin[0]; l1 = blin[1];
        #pragma unroll
        for (int k = 0; k < 32; ++k) {
            l0 += ps[k * 2 + 0];
            l1 += ps[k * 2 + 1];
        }
    } else {
        l0 = blin[0]; l1 = blin[1];
        const float* ps = plog + ((long)(s - 14) * BATCH + b) * 32;
        #pragma unroll
        for (int k = 0; k < 16; ++k) {
            l0 += ps[k * 2 + 0];
            l1 += ps[k * 2 + 1];
        }
    }
    float mx = fmaxf(l0, l1);
    float e0 = __expf(l0 - mx), e1 = __expf(l1 - mx);
    float p0 = e0 / (e0 + e1), p1 = e1 / (e0 + e1);
    if (s > 0) {
        const int cd = __popc(wv & ((1u << s) - 1));
        const float cdf = (float)cd, cuf = (float)(s - cd);
        const float ku = 16.f - cuf, kd = 16.f - cdf;
        const int n = NSPIN - s;
        const int kui = (int)fminf(fmaxf(ku, 0.f), 32.f);
        const int kdi = (int)fminf(fmaxf(kd, 0.f), 32.f);
        const float wu = fact[n] / fact[kui] * (ku >= 0.f ? 1.f : 0.f) + 1e-12f;
        const float wd = fact[n] / fact[kdi] * (kd >= 0.f ? 1.f : 0.f) + 1e-12f;
        p0 *= wu; p1 *= wd;
    }
    float inv = 1.f / (p0 + p1);
    out[idx * 2 + 0] = p0 * inv;
    out[idx * 2 + 1] = p1 * inv;
}

// ---------------- launch ----------------

extern "C" void kernel_launch(void* const* d_in, const int* in_sizes, int n_in,
                              void* d_out, int out_size, void* d_ws, size_t ws_size,
                              hipStream_t stream) {
    const float* din  = (const float*)d_in[0];  // [32][8192][2]
    const float* Wih  = (const float*)d_in[1];  // [1024][2]
    const float* Whh  = (const float*)d_in[2];  // [1024][1024]
    const float* bih  = (const float*)d_in[3];  // [1024]
    const float* bhh  = (const float*)d_in[4];  // [1024]
    const float* Wlin = (const float*)d_in[5];  // [2][1024]
    const float* blin = (const float*)d_in[6];  // [2]
    float* out = (float*)d_out;

    char* ws = (char*)d_ws;
    size_t o = 0;
    auto alloc = [&](size_t b) { size_t r = o; o += (b + 255) & ~(size_t)255; return r; };
    bf16*  Wbf  = (bf16*)(ws + alloc((size_t)HID * HID * 2));
    float* u0   = (float*)(ws + alloc(HID * 4));
    float* u1   = (float*)(ws + alloc(HID * 4));
    bf16*  hrow = (bf16*)(ws + alloc((size_t)64 * HID * 2));   // 64-row padded root
    float* l0s  = (float*)(ws + alloc(2 * 4));
    float* fact = (float*)(ws + alloc(33 * 4));
    unsigned int* words = (unsigned int*)(ws + alloc((size_t)BATCH * 4));
    unsigned int* pidx  = (unsigned int*)(ws + alloc((size_t)BATCH * 4));
    bf16*  hA   = (bf16*)(ws + alloc((size_t)BATCH * HID * 2));
    bf16*  hB   = (bf16*)(ws + alloc((size_t)BATCH * HID * 2));
    float* slog = (float*)(ws + alloc(((size_t)(1 << 14) - 2) * 64 * 4));  // ~4.2 MB
    float* plog = (float*)(ws + alloc(18L * BATCH * 32 * 4));              // 18.9 MB

    prep1<<<1024, 256, 0, stream>>>(din, Wih, Whh, bih, bhh, Wbf, u0, u1, words, pidx, fact);
    prep2<<<1, 1024, 0, stream>>>(u0, Wlin, blin, hrow, l0s);

    // tree levels: level i consumes 2^(i-1) states, emits 2^i (states at step i)
    const bf16* tin = hrow;
    bf16* tout = hA;
    for (int i = 1; i <= 13; ++i) {
        int Min = 1 << (i - 1);
        dim3 g(Min < 64 ? 1 : Min / 64, 8);
        tree_step<<<g, 512, 0, stream>>>(
            tin, tout, Wbf, u0, u1, Wlin,
            slog + ((long)(1 << i) - 2) * 64, Min);
        tin = tout;
        tout = (tout == hA) ? hB : hA;
    }
    // tin = states13 (hA); s=14 reads through pidx permutation directly.
    bf16* hin = (bf16*)tin;                 // hA (states13)
    bf16* hout = (tin == hA) ? hB : hA;     // hB
    for (int s = 14; s <= 31; ++s) {
        gemm_step<<<dim3(64, 4), 512, 0, stream>>>(
            hin, hout, Wbf, u0, u1, words,
            (s == 14) ? pidx : (const unsigned int*)nullptr,
            s - 1, (s < 31) ? 1 : 0, Wlin,
            plog + (size_t)(s - 14) * BATCH * 32);
        bf16* t = hin; hin = hout; hout = t;
    }
    finalize<<<(NSPIN * BATCH) / 256, 256, 0, stream>>>(plog, slog, l0s, blin, words, fact, out);
}